// Round 1
// baseline (264.771 us; speedup 1.0000x reference)
//
#include <hip/hip_runtime.h>

// ---------------------------------------------------------------------------
// MHA: out = softmax_causal((xWq)(xWk)^T / sqrt(64)) (xWv) Wo
// B=4 T=2048 D=1024 H=16 Dh=64.  All matmuls in bf16 MFMA (fp32 accum).
// R9: QKV GEMM ported to the 256x256 / BK=64 8-phase schedule (T2 XOR LDS
// swizzle via pre-swizzled global source + T3/T4 counted vmcnt(6) + T5
// setprio).  2-slot LDS ring (even K-tiles slot0, odd slot1), 1 half-tile
// staged per phase with 3-4 phase lag; vmcnt(6) only at phases 4/8.
// ---------------------------------------------------------------------------

typedef short  short8  __attribute__((ext_vector_type(8)));
typedef short  short4v __attribute__((ext_vector_type(4)));
typedef float  floatx4 __attribute__((ext_vector_type(4)));
typedef unsigned uint2v __attribute__((ext_vector_type(2)));

#define T_SZ 2048
#define DM   1024

// 0.125 (Dh^-0.5) * log2(e): softmax in base-2 domain -> native v_exp_f32
#define QSCALE 0.18033688011112042f

__device__ __forceinline__ short f2bf(float f) {
  unsigned u = __float_as_uint(f);
  u += 0x7fffu + ((u >> 16) & 1u);        // RNE
  return (short)(u >> 16);
}

#if defined(__has_builtin) && __has_builtin(__builtin_amdgcn_cvt_pk_bf16_f32)
typedef __bf16 bf16x2_t __attribute__((ext_vector_type(2)));
__device__ __forceinline__ unsigned pack_bf(float lo, float hi) {   // 1 VALU op
  return __builtin_bit_cast(unsigned, __builtin_amdgcn_cvt_pk_bf16_f32(lo, hi));
}
#else
__device__ __forceinline__ unsigned pack_bf(float lo, float hi) {   // 3 VALU ops
  return __builtin_amdgcn_perm(__float_as_uint(hi) + 0x8000u,
                               __float_as_uint(lo) + 0x8000u, 0x07060302u);
}
#endif

#if defined(__has_builtin) && __has_builtin(__builtin_amdgcn_exp2f)
__device__ __forceinline__ float fexp2(float x) { return __builtin_amdgcn_exp2f(x); }
#else
__device__ __forceinline__ float fexp2(float x) { return exp2f(x); }
#endif

__device__ __forceinline__ void gll16(const void* g, void* l) {
  __builtin_amdgcn_global_load_lds((const __attribute__((address_space(1))) void*)g,
                                   (__attribute__((address_space(3))) void*)l, 16, 0, 0);
}

#define SBAR() asm volatile("s_barrier" ::: "memory")
#define WLG()  asm volatile("s_waitcnt lgkmcnt(0)" ::: "memory")
#define WV6()  asm volatile("s_waitcnt vmcnt(6)" ::: "memory")
#define WV0()  asm volatile("s_waitcnt vmcnt(0)" ::: "memory")

// -------------------------------------------------- converts, one launch
// z in [0,4): W[z] fp32 [K,N] -> bf16 W^T [N,K]   (grid x,y = 32,32; block 32x8)
// z == 4   : x fp32 -> bf16 flat
__global__ void cvt_kernel(const float* __restrict__ s0, const float* __restrict__ s1,
                           const float* __restrict__ s2, const float* __restrict__ s3,
                           short* __restrict__ dst,
                           const float* __restrict__ x, short* __restrict__ xb) {
  const int tx = threadIdx.x, ty = threadIdx.y;       // block (32,8)
  if (blockIdx.z == 4) {                              // ---- x -> bf16
    const int tid = ty * 32 + tx;
    const int blk = blockIdx.y * 32 + blockIdx.x;     // 0..1023
    int i = (blk * 256 + tid) * 4;
#pragma unroll
    for (int j = 0; j < 8; ++j) {
      const float4 v = *(const float4*)(x + i);
      short4v o;
      o.x = f2bf(v.x); o.y = f2bf(v.y); o.z = f2bf(v.z); o.w = f2bf(v.w);
      *(short4v*)(xb + i) = o;
      i += 1048576;
    }
    return;
  }
  const float* srcs[4] = {s0, s1, s2, s3};
  const float* src = srcs[blockIdx.z];
  short* d = dst + (size_t)blockIdx.z * 1048576;
  __shared__ float tile[32][33];
  const int n_base = blockIdx.x * 32, k_base = blockIdx.y * 32;
#pragma unroll
  for (int j = 0; j < 4; ++j)
    tile[ty + j * 8][tx] = src[(size_t)(k_base + ty + j * 8) * 1024 + n_base + tx];
  __syncthreads();
#pragma unroll
  for (int j = 0; j < 4; ++j)
    d[(size_t)(n_base + ty + j * 8) * 1024 + k_base + tx] = f2bf(tile[tx][ty + j * 8]);
}

// -------------------------------------------------- QKV GEMM, 256x256 8-phase
// C = A[8192,1024] * Bt[3072,1024]^T.  512 thr (8 waves, 2M x 4N), BK=64.
// LDS: per matrix 2 K-tile slots x 2 halves x [128][64] bf16 (64 KB each).
// XOR swizzle: physical 16B-block = logical ^ (row&7), applied on the global
// source (stage) and on the ds_read address (linear LDS dest for gll16).
// Per iter t: compute kt0=2t (slot0, phases 1-4) and kt1=2t+1 (slot1, 5-8),
// quadrant (i-half, j-half) per phase; stage 1 half-tile/phase:
//   p1: kt1.A1 | p2-5: kt+2 {B0,B1,A0,A1} -> slot0 | p6-8: kt+3 {B0,B1,A0}
// vmcnt(6) at p4/p8 (3 half-tiles in flight).  Epilogue: Q(scaled)/K scatter
// bf16 [bh][t][64]; V -> V^T [bh][64][t].
__global__ __launch_bounds__(512, 2) void gemm_qkv(
    const short* __restrict__ A, const short* __restrict__ Bt,
    short* __restrict__ obf, short* __restrict__ vt) {
  __shared__ short As[32768];        // [slot][half][128][64]  64 KB
  __shared__ short Bs[32768];        // [slot][half][128][64]  64 KB
  const int tid  = threadIdx.x;
  const int w    = tid >> 6, lane = tid & 63;
  const int quad = lane >> 4, l15 = lane & 15;
  const int wr   = w >> 2, wc = w & 3;            // 2M x 4N waves
  const int fx   = l15 & 7;
  const int lid  = (int)blockIdx.x;
  // XCD-chunked: xcd = lid&7 owns 4 m-stripes (2 MB A -> L2), walks n.
  const int m0   = ((lid & 7) * 4 + ((lid >> 3) & 3)) * 256;
  const int n0   = (lid >> 5) * 256;
  // staging: thread covers rows srow, srow+64 of a half, 16B block (tid&7);
  // global col pre-swizzled so linear LDS ends up XOR-swizzled.
  const int srow = tid >> 3;
  const int scol = ((tid & 7) ^ (srow & 7)) * 8;

  const short* Ag = A  + (size_t)(m0 + srow) * 1024 + scol;
  const short* Bg = Bt + (size_t)(n0 + srow) * 1024 + scol;
  // per-wave LDS read bases (own half only)
  const short* Ab[2] = { &As[(0 * 2 + wr) * 8192], &As[(1 * 2 + wr) * 8192] };
  const short* Bb[2] = { &Bs[(0 * 2 + (wc >> 1)) * 8192], &Bs[(1 * 2 + (wc >> 1)) * 8192] };
  const int br0 = (wc & 1) * 64;

  floatx4 acc[8][4] = {};
  short8 af[4][2], bf[4][2];

#define STG_A(slot, h, kb) do { \
    short* _lb = &As[((slot) * 2 + (h)) * 8192 + tid * 8]; \
    const short* _gp = Ag + (size_t)(h) * (128 * 1024) + (kb); \
    gll16(_gp, _lb); \
    gll16(_gp + (size_t)(64 * 1024), _lb + 4096); \
  } while (0)
#define STG_B(slot, h, kb) do { \
    short* _lb = &Bs[((slot) * 2 + (h)) * 8192 + tid * 8]; \
    const short* _gp = Bg + (size_t)(h) * (128 * 1024) + (kb); \
    gll16(_gp, _lb); \
    gll16(_gp + (size_t)(64 * 1024), _lb + 4096); \
  } while (0)
#define LDA4(slot, ih) do { \
    _Pragma("unroll") for (int ii = 0; ii < 4; ++ii) \
    _Pragma("unroll") for (int s = 0; s < 2; ++s) \
      af[ii][s] = *(const short8*)&Ab[slot][(((ih) * 4 + ii) * 16 + l15) * 64 + (((s * 4 + quad) ^ fx)) * 8]; \
  } while (0)
#define LDB8(slot) do { \
    _Pragma("unroll") for (int j = 0; j < 4; ++j) \
    _Pragma("unroll") for (int s = 0; s < 2; ++s) \
      bf[j][s] = *(const short8*)&Bb[slot][(br0 + j * 16 + l15) * 64 + (((s * 4 + quad) ^ fx)) * 8]; \
  } while (0)
#define MMQ(ih, jh) do { \
    __builtin_amdgcn_s_setprio(1); \
    _Pragma("unroll") for (int ii = 0; ii < 4; ++ii) \
    _Pragma("unroll") for (int jj = 0; jj < 2; ++jj) \
    _Pragma("unroll") for (int s = 0; s < 2; ++s) \
      acc[(ih) * 4 + ii][(jh) * 2 + jj] = __builtin_amdgcn_mfma_f32_16x16x32_bf16( \
          af[ii][s], bf[(jh) * 2 + jj][s], acc[(ih) * 4 + ii][(jh) * 2 + jj], 0, 0, 0); \
    __builtin_amdgcn_s_setprio(0); \
  } while (0)

  // prologue: kt0 -> slot0 (A0,A1,B0,B1); kt1 -> slot1 (B0,B1,A0); A1 at p1.
  STG_A(0, 0, 0);  STG_A(0, 1, 0);
  STG_B(0, 0, 0);  STG_B(0, 1, 0);
  STG_B(1, 0, 64); STG_B(1, 1, 64);
  STG_A(1, 0, 64);
  WV6(); SBAR();

  for (int t = 0; t < 8; ++t) {
    const int kp1 = (2 * t + 1) * 64;          // kt1 (A1 staged at p1)
    const int kn2 = (2 * t + 2) * 64;          // -> slot0
    const int kn3 = (2 * t + 3) * 64;          // -> slot1
    const bool mre = (t < 7);
    // ---- p1: read kt0 frags (i0-3 + all B), stage kt1.A1
    LDA4(0, 0); LDB8(0);
    STG_A(1, 1, kp1);
    SBAR(); WLG(); MMQ(0, 0); SBAR();
    // ---- p2
    if (mre) STG_B(0, 0, kn2);
    SBAR(); MMQ(0, 1); SBAR();
    // ---- p3
    LDA4(0, 1);
    if (mre) STG_B(0, 1, kn2);
    SBAR(); WLG(); MMQ(1, 0); SBAR();
    // ---- p4
    if (mre) { STG_A(0, 0, kn2); WV6(); } else { WV0(); }
    SBAR(); MMQ(1, 1); SBAR();
    // ---- p5: read kt1 frags
    LDA4(1, 0); LDB8(1);
    if (mre) STG_A(0, 1, kn2);
    SBAR(); WLG(); MMQ(0, 0); SBAR();
    // ---- p6
    if (mre) STG_B(1, 0, kn3);
    SBAR(); MMQ(0, 1); SBAR();
    // ---- p7
    LDA4(1, 1);
    if (mre) STG_B(1, 1, kn3);
    SBAR(); WLG(); MMQ(1, 0); SBAR();
    // ---- p8
    if (mre) { STG_A(1, 0, kn3); WV6(); }
    SBAR(); MMQ(1, 1); SBAR();
  }

  // ---- epilogue (QKV scatter; same fragment->element map as before)
  const int wsel  = n0 >> 10;                   // 0=Q 1=K 2=V, uniform/block
  const int ncol0 = (n0 & 1023) + wc * 64;
  if (wsel < 2) {
    const float scale = (wsel == 0) ? QSCALE : 1.0f;
    short* outw = obf + (size_t)wsel * (64u * 2048u * 64u);
#pragma unroll
    for (int i = 0; i < 8; ++i) {
      const int row0 = m0 + wr * 128 + i * 16 + quad * 4;
#pragma unroll
      for (int j = 0; j < 4; ++j) {
        const int col = ncol0 + j * 16 + l15;
        const int h = col >> 6, d = col & 63;
#pragma unroll
        for (int r = 0; r < 4; ++r) {
          const int rg = row0 + r;
          const int b = rg >> 11, tt = rg & 2047;
          outw[(((size_t)(b * 16 + h) * 2048 + tt) << 6) + d] = f2bf(acc[i][j][r] * scale);
        }
      }
    }
  } else {                         // V -> V^T [bh][d][2048], 4 consecutive t/lane
#pragma unroll
    for (int i = 0; i < 8; ++i) {
      const int row0 = m0 + wr * 128 + i * 16 + quad * 4;
      const int b = row0 >> 11, tt = row0 & 2047;
#pragma unroll
      for (int j = 0; j < 4; ++j) {
        const int col = ncol0 + j * 16 + l15;
        const int h = col >> 6, d = col & 63;
        short4v pv;
#pragma unroll
        for (int r = 0; r < 4; ++r) pv[r] = f2bf(acc[i][j][r]);
        *(short4v*)(vt + (((size_t)(b * 16 + h) * 64 + d) << 11) + tt) = pv;
      }
    }
  }
#undef STG_A
#undef STG_B
#undef LDA4
#undef LDB8
#undef MMQ
}

// -------------------------------------------------- GEMM  C = A[M,K] * Bt[N,K]^T
// (retained for the Wo projection, MODE 1)
template <int MODE>
__global__ void gemm_bt(const short* __restrict__ A, const short* __restrict__ Bt,
                        short* __restrict__ obf, short* __restrict__ vt,
                        float* __restrict__ of, int K) {
  __shared__ short As[128 * 32];
  __shared__ short Bs[128 * 32];
  const int tid  = threadIdx.x;
  const int w    = tid >> 6, lane = tid & 63;
  const int quad = lane >> 4, l15 = lane & 15;
  const int wr   = w >> 1, wc = w & 1;
  const int lid  = (int)blockIdx.y * 64 + (int)blockIdx.x;
  const int m0   = (((lid & 7) + 8 * ((lid >> 3) & 7))) * 128;
  const int n0   = (lid >> 6) * 128;
  const int arow = tid >> 2, apart = tid & 3;

  floatx4 acc[4][4] = {};

  for (int kk = 0; kk < K; kk += 32) {
    gll16(A  + (size_t)(m0 + arow) * K      + kk + apart * 8, &As[tid * 8]);
    gll16(A  + (size_t)(m0 + 64 + arow) * K + kk + apart * 8, &As[(256 + tid) * 8]);
    gll16(Bt + (size_t)(n0 + arow) * K      + kk + apart * 8, &Bs[tid * 8]);
    gll16(Bt + (size_t)(n0 + 64 + arow) * K + kk + apart * 8, &Bs[(256 + tid) * 8]);
    __syncthreads();
    short8 af[4], bfr[4];
#pragma unroll
    for (int i = 0; i < 4; ++i)
      af[i] = *(const short8*)&As[(wr * 64 + i * 16 + l15) * 32 + quad * 8];
#pragma unroll
    for (int j = 0; j < 4; ++j)
      bfr[j] = *(const short8*)&Bs[(wc * 64 + j * 16 + l15) * 32 + quad * 8];
#pragma unroll
    for (int i = 0; i < 4; ++i)
#pragma unroll
      for (int j = 0; j < 4; ++j)
        acc[i][j] = __builtin_amdgcn_mfma_f32_16x16x32_bf16(af[i], bfr[j], acc[i][j], 0, 0, 0);
    __syncthreads();
  }

  if (MODE == 0) {
    const int wsel = n0 >> 10;
    const int ncol0 = (n0 & 1023) + wc * 64;
    if (wsel < 2) {
      const float scale = (wsel == 0) ? QSCALE : 1.0f;
      short* outw = obf + (size_t)wsel * (64u * 2048u * 64u);
#pragma unroll
      for (int i = 0; i < 4; ++i) {
        const int row0 = m0 + wr * 64 + i * 16 + quad * 4;
#pragma unroll
        for (int j = 0; j < 4; ++j) {
          const int col = ncol0 + j * 16 + l15;
          const int h = col >> 6, d = col & 63;
#pragma unroll
          for (int r = 0; r < 4; ++r) {
            const int rg = row0 + r;
            const int b = rg >> 11, t = rg & 2047;
            outw[(((size_t)(b * 16 + h) * 2048 + t) << 6) + d] = f2bf(acc[i][j][r] * scale);
          }
        }
      }
    } else {
#pragma unroll
      for (int i = 0; i < 4; ++i) {
        const int row0 = m0 + wr * 64 + i * 16 + quad * 4;
        const int b = row0 >> 11, t = row0 & 2047;
#pragma unroll
        for (int j = 0; j < 4; ++j) {
          const int col = ncol0 + j * 16 + l15;
          const int h = col >> 6, d = col & 63;
          short4v pv;
#pragma unroll
          for (int r = 0; r < 4; ++r) pv[r] = f2bf(acc[i][j][r]);
          *(short4v*)(vt + (((size_t)(b * 16 + h) * 64 + d) << 11) + t) = pv;
        }
      }
    }
  } else {
#pragma unroll
    for (int i = 0; i < 4; ++i) {
      const int row0 = m0 + wr * 64 + i * 16 + quad * 4;
#pragma unroll
      for (int j = 0; j < 4; ++j) {
        const int col = n0 + wc * 64 + j * 16 + l15;
#pragma unroll
        for (int r = 0; r < 4; ++r)
          of[(size_t)(row0 + r) * 1024 + col] = acc[i][j][r];
      }
    }
  }
}

// -------------------------------------------------- flash attention (causal, transposed)
// grid (8, 64), block 256 (4 waves).  bh = bx + 8*(by&7) -> one XCD per bh
// group (K/V L2-local).  Block does q-tiles p and 15-p sequentially (17
// staging iters, uniform).  Each wave owns 32 q rows (strips A/B of 16):
// every kf/vf LDS frag read feeds BOTH strips -> ~2x less LDS read traffic
// per q than the 8-wave/16-q layout.  One lane per q.  BN=128 k-cols/iter.
// l = softmax denominator accumulated by MFMA against ones-row 64 of Vs.
__global__ __launch_bounds__(256, 2) void attn_kernel(
    const short* __restrict__ Qg, const short* __restrict__ Kg,
    const short* __restrict__ Vt, short* __restrict__ ctx) {
  __shared__ short Ks[128 * 72];       // [t_k][d]          18.00 KB
  __shared__ short Vs[80 * 132];       // [d][t_k], d=64 -> ones row   20.63 KB
  __shared__ short Ps[4 * 32 * 136];   // per-wave [q(32)][t_k]        34.00 KB

  const int tid  = threadIdx.x;
  const int w    = tid >> 6, lane = tid & 63;
  const int quad = lane >> 4, l15 = lane & 15;
  const int bh = (int)blockIdx.x + 8 * ((int)blockIdx.y & 7);
  const int p  = (int)blockIdx.y >> 3;          // q-pair: tiles p and 15-p
  const int b  = bh >> 4, h = bh & 15;

  const size_t base = (size_t)bh * (T_SZ * 64);
  const short* Qb  = Qg + base;
  const short* Kb  = Kg + base;
  const short* Vtb = Vt + base;
  short* Pw = &Ps[w * (32 * 136)];

  // staging (256 thr): K row skr cols [skc,skc+32); V row svr cols [svc,svc+32)
  const int skr = tid >> 1, skc = (tid & 1) * 32;
  const int svr = tid >> 2, svc = (tid & 3) * 32;

  // init Vs rows 64..79: row 64 = 1.0 (l-reduction), 65..79 = 0
  {
    const int rr = 64 + (tid >> 4), cb = (tid & 15) * 8;
    const short vv = (tid < 16) ? (short)0x3F80 : (short)0;
    short8 fill;
#pragma unroll
    for (int j = 0; j < 8; ++j) fill[j] = vv;
    *(short8*)&Vs[rr * 132 + cb] = fill;
  }

  for (int qsel = 0; qsel < 2; ++qsel) {
    const int qi = qsel ? (15 - p) : p;
    const int q0 = qi << 7;
    const int rowA = q0 + w * 32;              // strip A (16 q), strip B = +16
    const int rowB = rowA + 16;

    const short8 qA0 = *(const short8*)(Qb + (size_t)(rowA + l15) * 64 + quad * 8);
    const short8 qA1 = *(const short8*)(Qb + (size_t)(rowA + l15) * 64 + 32 + quad * 8);
    const short8 qB0 = *(const short8*)(Qb + (size_t)(rowB + l15) * 64 + quad * 8);
    const short8 qB1 = *(const short8*)(Qb + (size_t)(rowB + l15) * 64 + 32 + quad * 8);

    floatx4 OA[4] = {}, OB[4] = {};
    floatx4 O5A = {}, O5B = {};                // row: l in quad0/reg0

    const int ktiles = qi + 1;
    // preload tile 0 into registers
    short8 kR[4], vR[4];
#pragma unroll
    for (int j = 0; j < 4; ++j) {
      kR[j] = *(const short8*)(Kb + (size_t)skr * 64 + skc + j * 8);
      vR[j] = *(const short8*)(Vtb + (size_t)svr * 2048 + svc + j * 8);
    }

    for (int kt = 0; kt < ktiles; ++kt) {
      const int k0 = kt << 7;
      __syncthreads();                         // prior tile's LDS reads done
#pragma unroll
      for (int j = 0; j < 4; ++j) {
        *(short8*)&Ks[skr * 72 + skc + j * 8] = kR[j];
        *(short8*)&Vs[svr * 132 + svc + j * 8] = vR[j];
      }
      if (kt + 1 < ktiles) {                   // prefetch next tile
        const int kn = (kt + 1) << 7;
#pragma unroll
        for (int j = 0; j < 4; ++j) {
          kR[j] = *(const short8*)(Kb + (size_t)(kn + skr) * 64 + skc + j * 8);
          vR[j] = *(const short8*)(Vtb + (size_t)svr * 2048 + kn + svc + j * 8);
        }
      }
      __syncthreads();                         // staged LDS visible

      const int dkA = rowA - k0;               // >= 0
      const int dkB = dkA + 16;
      const int limA = dkA + l15, limB = limA + 16;
      const int naA = min(8, (dkA >> 4) + 1), nchA = (naA + 1) >> 1;
      const int naB = min(8, (dkB >> 4) + 1), nchB = (naB + 1) >> 1;

#pragma unroll
      for (int mt = 0; mt < 8; ++mt) {
        const int pa = l15 * 136 + mt * 16 + quad * 4;          // strip A P addr
        const int pb = (16 + l15) * 136 + mt * 16 + quad * 4;   // strip B P addr
        const bool actA = (mt * 16 < dkA + 16);
        const bool actB = (mt * 16 < dkB + 16);
        if (actB) {
          const short8 kf0 = *(const short8*)&Ks[(mt * 16 + l15) * 72 + quad * 8];
          const short8 kf1 = *(const short8*)&Ks[(mt * 16 + l15) * 72 + 32 + quad * 8];
          {                                    // ---- strip B
            floatx4 s = {};
            s = __builtin_amdgcn_mfma_f32_16x16x32_bf16(kf0, qB0, s, 0, 0, 0);
            s = __builtin_amdgcn_mfma_f32_16x16x32_bf16(kf1, qB1, s, 0, 0, 0);
            if (mt * 16 + 15 > dkB) {
#pragma unroll
              for (int r = 0; r < 4; ++r)
                if (mt * 16 + quad * 4 + r > limB) s[r] = -1e30f;
            }
            floatx4 e;
#pragma unroll
            for (int r = 0; r < 4; ++r) e[r] = fexp2(s[r]);
            uint2v pd;
            pd.x = pack_bf(e[0], e[1]);
            pd.y = pack_bf(e[2], e[3]);
            *(uint2v*)&Pw[pb] = pd;
          }
          if (actA) {                          // ---- strip A (reuses kf)
            floatx4 s = {};
            s = __builtin_amdgcn_mfma_f32_16x16x32_bf16(kf0, qA0, s, 0, 0, 0);
            s = __builtin_amdgcn_mfma_f32_16x16x32_bf16(kf1, qA1, s, 0, 0, 0);
            if (mt * 16 + 15 > dkA) {
#pragma unroll
              for (int r = 0; r < 4; ++r)
                if (mt * 16 + quad * 4 + r > limA) s[r] = -1e30f;
            }
            floatx4 e;
#pragma unroll
            for (int r = 0; r < 4; ++r) e[r] = fexp2(s[r]);
            uint2v pd;
            pd.x = pack_bf(e[0], e[1]);
            pd.y = pack_bf(e[2], e[3]);
            *(uint2v*)&Pw[pa] = pd;
          } else if (mt < 2 * nchA) {
            uint2v z; z.x = 0; z.y = 0;
            *(uint2v*)&Pw[pa] = z;
          }
        } else {                               // actB false => actA false
          uint2v z; z.x = 0; z.y = 0;
          if (mt < 2 * nchB) *(uint2v*)&Pw[pb] = z;
          if (mt < 2 * nchA) *(uint2v*)&Pw[pa] = z;
        }
      }

#pragma unroll
      for (int c = 0; c < 4; ++c) {
        if (c < nchB) {
          const short8 vfl = *(const short8*)&Vs[(64 + l15) * 132 + c * 32 + quad * 8];
          short8 vf[4];
#pragma unroll
          for (int dt = 0; dt < 4; ++dt)
            vf[dt] = *(const short8*)&Vs[(dt * 16 + l15) * 132 + c * 32 + quad * 8];
          const short8 pfB = *(const short8*)&Pw[(16 + l15) * 136 + c * 32 + quad * 8];
#pragma unroll
          for (int dt = 0; dt < 4; ++dt)
            OB[dt] = __builtin_amdgcn_mfma_f32_16x16x32_bf16(vf[dt], pfB, OB[dt], 0, 0, 0);
          O5B = __builtin_amdgcn_mfma_f32_16x16x32_bf16(vfl, pfB, O5B, 0, 0, 0);
          if (c < nchA) {                      // reuses vf/vfl
            const short8 pfA = *(const short8*)&Pw[l15 * 136 + c * 32 + quad * 8];
#pragma unroll
            for (int dt = 0; dt < 4; ++dt)
              OA[dt] = __builtin_amdgcn_mfma_f32_16x16x32_bf16(vf[dt], pfA, OA[dt], 0, 0, 0);
            O5A = __builtin_amdgcn_mfma_f32_16x16x32_bf16(vfl, pfA, O5A, 0, 0, 0);
          }
        }
      }
    }

    // epilogue: l = O5[0] of quad0 lane l15 (C-layout row 0 = ones-row d=64)
    {
      const float lA = __shfl(O5A[0], l15);
      const float invA = 1.0f / lA;
      const int t = rowA + l15;
      short* cb = ctx + (((size_t)(b * T_SZ + t)) << 10) + h * 64 + quad * 4;
#pragma unroll
      for (int dt = 0; dt < 4; ++dt) {
        short4v o4;
#pragma unroll
        for (int r = 0; r < 4; ++r) o4[r] = f2bf(OA[dt][r] * invA);
        *(short4v*)(cb + dt * 16) = o4;
      }
    }
    {
      const float lB = __shfl(O5B[0], l15);
      const float invB = 1.0f / lB;
      const int t = rowB + l15;
      short* cb = ctx + (((size_t)(b * T_SZ + t)) << 10) + h * 64 + quad * 4;
#pragma unroll
      for (int dt = 0; dt < 4; ++dt) {
        short4v o4;
#pragma unroll
        for (int r = 0; r < 4; ++r) o4[r] = f2bf(OB[dt][r] * invB);
        *(short4v*)(cb + dt * 16) = o4;
      }
    }
  }
}

// --------------------------------------------------
extern "C" void kernel_launch(void* const* d_in, const int* in_sizes, int n_in,
                              void* d_out, int out_size, void* d_ws, size_t ws_size,
                              hipStream_t stream) {
  const float* x  = (const float*)d_in[0];
  const float* Wq = (const float*)d_in[1];
  const float* Wk = (const float*)d_in[2];
  const float* Wv = (const float*)d_in[3];
  const float* Wo = (const float*)d_in[4];
  float* out = (float*)d_out;

  // bf16 workspace (72 MB):
  //   xb [8M]  : x bf16; dead after gemm_qkv -> reused as ctx
  //   Wt [4x1M]: transposed weights
  //   Qb,Kb [8M each] : projections [bh][t][64]
  //   Vt [8M]  : V^T [bh][64][t]  (written directly by gemm_qkv epilogue)
  short* ws  = (short*)d_ws;
  short* xb  = ws;
  short* Wt  = ws + 8388608;
  short* Qb  = Wt + 4 * 1048576;
  short* Kb  = Qb + 8388608;
  short* Vt  = Kb + 8388608;
  short* ctx = xb;

  cvt_kernel<<<dim3(32, 32, 5), dim3(32, 8), 0, stream>>>(Wq, Wk, Wv, Wo, Wt, x, xb);
  gemm_qkv<<<dim3(384), 512, 0, stream>>>(xb, Wt, Qb, Vt);
  attn_kernel<<<dim3(8, 64), 256, 0, stream>>>(Qb, Kb, Vt, ctx);
  gemm_bt<1><<<dim3(64, 8), 256, 0, stream>>>(ctx, Wt + 3 * 1048576, nullptr, nullptr, out, 1024);
}

// Round 2
// 257.024 us; speedup vs baseline: 1.0301x; 1.0301x over previous
//
#include <hip/hip_runtime.h>

// ---------------------------------------------------------------------------
// MHA: out = softmax_causal((xWq)(xWk)^T / sqrt(64)) (xWv) Wo
// B=4 T=2048 D=1024 H=16 Dh=64.  All matmuls in bf16 MFMA (fp32 accum).
// R10: QKV back on the proven 128^2 gemm_bt<0> (8-phase 256^2 regressed:
// 384 blocks @ 1 block/CU = 1.5 dispatch rounds + K=1024 too short to
// amortize prologue).  attn: Vs/Ps LDS re-laid to stride-128 + 16B-block
// XOR swizzle (blk ^= row&7).  Old strides 132/136 gave word-strides
// 66==2, 68==4 (mod 32) -> V reads hit only even banks (2x), P reads only
// every-4th bank (4x) = the measured 6.46M SQ_LDS_BANK_CONFLICT cycles.
// ---------------------------------------------------------------------------

typedef short  short8  __attribute__((ext_vector_type(8)));
typedef short  short4v __attribute__((ext_vector_type(4)));
typedef float  floatx4 __attribute__((ext_vector_type(4)));
typedef unsigned uint2v __attribute__((ext_vector_type(2)));

#define T_SZ 2048
#define DM   1024

// 0.125 (Dh^-0.5) * log2(e): softmax in base-2 domain -> native v_exp_f32
#define QSCALE 0.18033688011112042f

__device__ __forceinline__ short f2bf(float f) {
  unsigned u = __float_as_uint(f);
  u += 0x7fffu + ((u >> 16) & 1u);        // RNE
  return (short)(u >> 16);
}

#if defined(__has_builtin) && __has_builtin(__builtin_amdgcn_cvt_pk_bf16_f32)
typedef __bf16 bf16x2_t __attribute__((ext_vector_type(2)));
__device__ __forceinline__ unsigned pack_bf(float lo, float hi) {   // 1 VALU op
  return __builtin_bit_cast(unsigned, __builtin_amdgcn_cvt_pk_bf16_f32(lo, hi));
}
#else
__device__ __forceinline__ unsigned pack_bf(float lo, float hi) {   // 3 VALU ops
  return __builtin_amdgcn_perm(__float_as_uint(hi) + 0x8000u,
                               __float_as_uint(lo) + 0x8000u, 0x07060302u);
}
#endif

#if defined(__has_builtin) && __has_builtin(__builtin_amdgcn_exp2f)
__device__ __forceinline__ float fexp2(float x) { return __builtin_amdgcn_exp2f(x); }
#else
__device__ __forceinline__ float fexp2(float x) { return exp2f(x); }
#endif

__device__ __forceinline__ void gll16(const void* g, void* l) {
  __builtin_amdgcn_global_load_lds((const __attribute__((address_space(1))) void*)g,
                                   (__attribute__((address_space(3))) void*)l, 16, 0, 0);
}

// -------------------------------------------------- converts, one launch
// z in [0,4): W[z] fp32 [K,N] -> bf16 W^T [N,K]   (grid x,y = 32,32; block 32x8)
// z == 4   : x fp32 -> bf16 flat
__global__ void cvt_kernel(const float* __restrict__ s0, const float* __restrict__ s1,
                           const float* __restrict__ s2, const float* __restrict__ s3,
                           short* __restrict__ dst,
                           const float* __restrict__ x, short* __restrict__ xb) {
  const int tx = threadIdx.x, ty = threadIdx.y;       // block (32,8)
  if (blockIdx.z == 4) {                              // ---- x -> bf16
    const int tid = ty * 32 + tx;
    const int blk = blockIdx.y * 32 + blockIdx.x;     // 0..1023
    int i = (blk * 256 + tid) * 4;
#pragma unroll
    for (int j = 0; j < 8; ++j) {
      const float4 v = *(const float4*)(x + i);
      short4v o;
      o.x = f2bf(v.x); o.y = f2bf(v.y); o.z = f2bf(v.z); o.w = f2bf(v.w);
      *(short4v*)(xb + i) = o;
      i += 1048576;
    }
    return;
  }
  const float* srcs[4] = {s0, s1, s2, s3};
  const float* src = srcs[blockIdx.z];
  short* d = dst + (size_t)blockIdx.z * 1048576;
  __shared__ float tile[32][33];
  const int n_base = blockIdx.x * 32, k_base = blockIdx.y * 32;
#pragma unroll
  for (int j = 0; j < 4; ++j)
    tile[ty + j * 8][tx] = src[(size_t)(k_base + ty + j * 8) * 1024 + n_base + tx];
  __syncthreads();
#pragma unroll
  for (int j = 0; j < 4; ++j)
    d[(size_t)(n_base + ty + j * 8) * 1024 + k_base + tx] = f2bf(tile[tx][ty + j * 8]);
}

// -------------------------------------------------- GEMM  C = A[M,K] * Bt[N,K]^T
// XCD-swizzled block mapping: lid%8 = XCD; each XCD owns 8 m-stripes (2 MB of
// A -> L2-resident) and walks n sequentially (B-tile hot).  gridDim.x must be 64.
// MODE 0: QKV epilogue.  Q (wsel0, scaled) / K (wsel1) -> bf16 [bh][t][64];
//         V (wsel2) -> V^T bf16 [bh][64][t] (transpose fused, 8B packed stores)
// MODE 1: fp32 row-major epilogue -> d_out
template <int MODE>
__global__ void gemm_bt(const short* __restrict__ A, const short* __restrict__ Bt,
                        short* __restrict__ obf, short* __restrict__ vt,
                        float* __restrict__ of, int K) {
  __shared__ short As[128 * 32];
  __shared__ short Bs[128 * 32];
  const int tid  = threadIdx.x;
  const int w    = tid >> 6, lane = tid & 63;
  const int quad = lane >> 4, l15 = lane & 15;
  const int wr   = w >> 1, wc = w & 1;
  const int lid  = (int)blockIdx.y * 64 + (int)blockIdx.x;
  const int m0   = (((lid & 7) + 8 * ((lid >> 3) & 7))) * 128;
  const int n0   = (lid >> 6) * 128;
  const int arow = tid >> 2, apart = tid & 3;

  floatx4 acc[4][4] = {};

  for (int kk = 0; kk < K; kk += 32) {
    gll16(A  + (size_t)(m0 + arow) * K      + kk + apart * 8, &As[tid * 8]);
    gll16(A  + (size_t)(m0 + 64 + arow) * K + kk + apart * 8, &As[(256 + tid) * 8]);
    gll16(Bt + (size_t)(n0 + arow) * K      + kk + apart * 8, &Bs[tid * 8]);
    gll16(Bt + (size_t)(n0 + 64 + arow) * K + kk + apart * 8, &Bs[(256 + tid) * 8]);
    __syncthreads();
    short8 af[4], bfr[4];
#pragma unroll
    for (int i = 0; i < 4; ++i)
      af[i] = *(const short8*)&As[(wr * 64 + i * 16 + l15) * 32 + quad * 8];
#pragma unroll
    for (int j = 0; j < 4; ++j)
      bfr[j] = *(const short8*)&Bs[(wc * 64 + j * 16 + l15) * 32 + quad * 8];
#pragma unroll
    for (int i = 0; i < 4; ++i)
#pragma unroll
      for (int j = 0; j < 4; ++j)
        acc[i][j] = __builtin_amdgcn_mfma_f32_16x16x32_bf16(af[i], bfr[j], acc[i][j], 0, 0, 0);
    __syncthreads();
  }

  if (MODE == 0) {
    const int wsel = n0 >> 10;
    const int ncol0 = (n0 & 1023) + wc * 64;
    if (wsel < 2) {
      const float scale = (wsel == 0) ? QSCALE : 1.0f;
      short* outw = obf + (size_t)wsel * (64u * 2048u * 64u);
#pragma unroll
      for (int i = 0; i < 4; ++i) {
        const int row0 = m0 + wr * 64 + i * 16 + quad * 4;
#pragma unroll
        for (int j = 0; j < 4; ++j) {
          const int col = ncol0 + j * 16 + l15;
          const int h = col >> 6, d = col & 63;
#pragma unroll
          for (int r = 0; r < 4; ++r) {
            const int rg = row0 + r;
            const int b = rg >> 11, t = rg & 2047;
            outw[(((size_t)(b * 16 + h) * 2048 + t) << 6) + d] = f2bf(acc[i][j][r] * scale);
          }
        }
      }
    } else {                         // V -> V^T [bh][d][2048], 4 consecutive t per lane
#pragma unroll
      for (int i = 0; i < 4; ++i) {
        const int row0 = m0 + wr * 64 + i * 16 + quad * 4;   // t base (mult of 4)
        const int b = row0 >> 11, t = row0 & 2047;
#pragma unroll
        for (int j = 0; j < 4; ++j) {
          const int col = ncol0 + j * 16 + l15;
          const int h = col >> 6, d = col & 63;
          short4v pv;
#pragma unroll
          for (int r = 0; r < 4; ++r) pv[r] = f2bf(acc[i][j][r]);
          *(short4v*)(vt + (((size_t)(b * 16 + h) * 64 + d) << 11) + t) = pv;
        }
      }
    }
  } else {
#pragma unroll
    for (int i = 0; i < 4; ++i) {
      const int row0 = m0 + wr * 64 + i * 16 + quad * 4;
#pragma unroll
      for (int j = 0; j < 4; ++j) {
        const int col = n0 + wc * 64 + j * 16 + l15;
#pragma unroll
        for (int r = 0; r < 4; ++r)
          of[(size_t)(row0 + r) * 1024 + col] = acc[i][j][r];
      }
    }
  }
}

// -------------------------------------------------- flash attention (causal, transposed)
// grid (8, 64), block 256 (4 waves).  bh = bx + 8*(by&7) -> one XCD per bh
// group (K/V L2-local).  Block does q-tiles p and 15-p sequentially (17
// staging iters, uniform).  Each wave owns 32 q rows (strips A/B of 16):
// every kf/vf LDS frag read feeds BOTH strips -> ~2x less LDS read traffic
// per q than the 8-wave/16-q layout.  One lane per q.  BN=128 k-cols/iter.
// l = softmax denominator accumulated by MFMA against ones-row 64 of Vs.
// R10 LDS layout: Vs [80][128] and Ps [32][128]/wave, 16B-block XOR swizzle
// blk' = blk ^ (row&7) on BOTH write and read -> balanced banks (Ks stride
// 72 is already balanced for its pattern: bank = 4*((l15+quad)&7)).
__global__ __launch_bounds__(256, 2) void attn_kernel(
    const short* __restrict__ Qg, const short* __restrict__ Kg,
    const short* __restrict__ Vt, short* __restrict__ ctx) {
  __shared__ short Ks[128 * 72];       // [t_k][d]                    18.00 KB
  __shared__ short Vs[80 * 128];       // [d][t_k] swz, d=64 -> ones  20.00 KB
  __shared__ short Ps[4 * 32 * 128];   // per-wave [q(32)][t_k] swz   32.00 KB

  const int tid  = threadIdx.x;
  const int w    = tid >> 6, lane = tid & 63;
  const int quad = lane >> 4, l15 = lane & 15;
  const int fx   = l15 & 7;                     // row-XOR for swizzled bufs
  const int bh = (int)blockIdx.x + 8 * ((int)blockIdx.y & 7);
  const int p  = (int)blockIdx.y >> 3;          // q-pair: tiles p and 15-p
  const int b  = bh >> 4, h = bh & 15;

  const size_t base = (size_t)bh * (T_SZ * 64);
  const short* Qb  = Qg + base;
  const short* Kb  = Kg + base;
  const short* Vtb = Vt + base;
  short* Pw = &Ps[w * (32 * 128)];

  // staging (256 thr): K row skr cols [skc,skc+32); V row svr cols [svc,svc+32)
  const int skr = tid >> 1, skc = (tid & 1) * 32;
  const int svr = tid >> 2, svq = tid & 3;
  const int sfx = svr & 7;                      // Vs write row-XOR

  // init Vs rows 64..79: row 64 = 1.0 (l-reduction), 65..79 = 0
  {
    const int rr = 64 + (tid >> 4);
    const int cb = (tid & 15) ^ ((tid >> 4) & 7);       // swizzled block
    const short vv = (tid < 16) ? (short)0x3F80 : (short)0;
    short8 fill;
#pragma unroll
    for (int j = 0; j < 8; ++j) fill[j] = vv;
    *(short8*)&Vs[rr * 128 + cb * 8] = fill;
  }

  for (int qsel = 0; qsel < 2; ++qsel) {
    const int qi = qsel ? (15 - p) : p;
    const int q0 = qi << 7;
    const int rowA = q0 + w * 32;              // strip A (16 q), strip B = +16
    const int rowB = rowA + 16;

    const short8 qA0 = *(const short8*)(Qb + (size_t)(rowA + l15) * 64 + quad * 8);
    const short8 qA1 = *(const short8*)(Qb + (size_t)(rowA + l15) * 64 + 32 + quad * 8);
    const short8 qB0 = *(const short8*)(Qb + (size_t)(rowB + l15) * 64 + quad * 8);
    const short8 qB1 = *(const short8*)(Qb + (size_t)(rowB + l15) * 64 + 32 + quad * 8);

    floatx4 OA[4] = {}, OB[4] = {};
    floatx4 O5A = {}, O5B = {};                // row: l in quad0/reg0

    const int ktiles = qi + 1;
    // preload tile 0 into registers
    short8 kR[4], vR[4];
#pragma unroll
    for (int j = 0; j < 4; ++j) {
      kR[j] = *(const short8*)(Kb + (size_t)skr * 64 + skc + j * 8);
      vR[j] = *(const short8*)(Vtb + (size_t)svr * 2048 + svq * 32 + j * 8);
    }

    for (int kt = 0; kt < ktiles; ++kt) {
      const int k0 = kt << 7;
      __syncthreads();                         // prior tile's LDS reads done
#pragma unroll
      for (int j = 0; j < 4; ++j) {
        *(short8*)&Ks[skr * 72 + skc + j * 8] = kR[j];
        *(short8*)&Vs[svr * 128 + ((svq * 4 + j) ^ sfx) * 8] = vR[j];
      }
      if (kt + 1 < ktiles) {                   // prefetch next tile
        const int kn = (kt + 1) << 7;
#pragma unroll
        for (int j = 0; j < 4; ++j) {
          kR[j] = *(const short8*)(Kb + (size_t)(kn + skr) * 64 + skc + j * 8);
          vR[j] = *(const short8*)(Vtb + (size_t)svr * 2048 + kn + svq * 32 + j * 8);
        }
      }
      __syncthreads();                         // staged LDS visible

      const int dkA = rowA - k0;               // >= 0
      const int dkB = dkA + 16;
      const int limA = dkA + l15, limB = limA + 16;
      const int naA = min(8, (dkA >> 4) + 1), nchA = (naA + 1) >> 1;
      const int naB = min(8, (dkB >> 4) + 1), nchB = (naB + 1) >> 1;

#pragma unroll
      for (int mt = 0; mt < 8; ++mt) {
        // swizzled P write addr: logical 16B-block = 2*mt + (quad>>1),
        // 8B sub-offset = (quad&1)*4; block XOR'd by q-row low bits (fx)
        const int pblk = ((2 * mt + (quad >> 1)) ^ fx) * 8 + (quad & 1) * 4;
        const int pa = l15 * 128 + pblk;                  // strip A
        const int pb = (16 + l15) * 128 + pblk;           // strip B
        const bool actA = (mt * 16 < dkA + 16);
        const bool actB = (mt * 16 < dkB + 16);
        if (actB) {
          const short8 kf0 = *(const short8*)&Ks[(mt * 16 + l15) * 72 + quad * 8];
          const short8 kf1 = *(const short8*)&Ks[(mt * 16 + l15) * 72 + 32 + quad * 8];
          {                                    // ---- strip B
            floatx4 s = {};
            s = __builtin_amdgcn_mfma_f32_16x16x32_bf16(kf0, qB0, s, 0, 0, 0);
            s = __builtin_amdgcn_mfma_f32_16x16x32_bf16(kf1, qB1, s, 0, 0, 0);
            if (mt * 16 + 15 > dkB) {
#pragma unroll
              for (int r = 0; r < 4; ++r)
                if (mt * 16 + quad * 4 + r > limB) s[r] = -1e30f;
            }
            floatx4 e;
#pragma unroll
            for (int r = 0; r < 4; ++r) e[r] = fexp2(s[r]);
            uint2v pd;
            pd.x = pack_bf(e[0], e[1]);
            pd.y = pack_bf(e[2], e[3]);
            *(uint2v*)&Pw[pb] = pd;
          }
          if (actA) {                          // ---- strip A (reuses kf)
            floatx4 s = {};
            s = __builtin_amdgcn_mfma_f32_16x16x32_bf16(kf0, qA0, s, 0, 0, 0);
            s = __builtin_amdgcn_mfma_f32_16x16x32_bf16(kf1, qA1, s, 0, 0, 0);
            if (mt * 16 + 15 > dkA) {
#pragma unroll
              for (int r = 0; r < 4; ++r)
                if (mt * 16 + quad * 4 + r > limA) s[r] = -1e30f;
            }
            floatx4 e;
#pragma unroll
            for (int r = 0; r < 4; ++r) e[r] = fexp2(s[r]);
            uint2v pd;
            pd.x = pack_bf(e[0], e[1]);
            pd.y = pack_bf(e[2], e[3]);
            *(uint2v*)&Pw[pa] = pd;
          } else if (mt < 2 * nchA) {
            uint2v z; z.x = 0; z.y = 0;
            *(uint2v*)&Pw[pa] = z;
          }
        } else {                               // actB false => actA false
          uint2v z; z.x = 0; z.y = 0;
          if (mt < 2 * nchB) *(uint2v*)&Pw[pb] = z;
          if (mt < 2 * nchA) *(uint2v*)&Pw[pa] = z;
        }
      }

#pragma unroll
      for (int c = 0; c < 4; ++c) {
        if (c < nchB) {
          const int vcb = ((4 * c + quad) ^ fx) * 8;       // swizzled V/P block
          const short8 vfl = *(const short8*)&Vs[(64 + l15) * 128 + vcb];
          short8 vf[4];
#pragma unroll
          for (int dt = 0; dt < 4; ++dt)
            vf[dt] = *(const short8*)&Vs[(dt * 16 + l15) * 128 + vcb];
          const short8 pfB = *(const short8*)&Pw[(16 + l15) * 128 + vcb];
#pragma unroll
          for (int dt = 0; dt < 4; ++dt)
            OB[dt] = __builtin_amdgcn_mfma_f32_16x16x32_bf16(vf[dt], pfB, OB[dt], 0, 0, 0);
          O5B = __builtin_amdgcn_mfma_f32_16x16x32_bf16(vfl, pfB, O5B, 0, 0, 0);
          if (c < nchA) {                      // reuses vf/vfl
            const short8 pfA = *(const short8*)&Pw[l15 * 128 + vcb];
#pragma unroll
            for (int dt = 0; dt < 4; ++dt)
              OA[dt] = __builtin_amdgcn_mfma_f32_16x16x32_bf16(vf[dt], pfA, OA[dt], 0, 0, 0);
            O5A = __builtin_amdgcn_mfma_f32_16x16x32_bf16(vfl, pfA, O5A, 0, 0, 0);
          }
        }
      }
    }

    // epilogue: l = O5[0] of quad0 lane l15 (C-layout row 0 = ones-row d=64)
    {
      const float lA = __shfl(O5A[0], l15);
      const float invA = 1.0f / lA;
      const int t = rowA + l15;
      short* cb = ctx + (((size_t)(b * T_SZ + t)) << 10) + h * 64 + quad * 4;
#pragma unroll
      for (int dt = 0; dt < 4; ++dt) {
        short4v o4;
#pragma unroll
        for (int r = 0; r < 4; ++r) o4[r] = f2bf(OA[dt][r] * invA);
        *(short4v*)(cb + dt * 16) = o4;
      }
    }
    {
      const float lB = __shfl(O5B[0], l15);
      const float invB = 1.0f / lB;
      const int t = rowB + l15;
      short* cb = ctx + (((size_t)(b * T_SZ + t)) << 10) + h * 64 + quad * 4;
#pragma unroll
      for (int dt = 0; dt < 4; ++dt) {
        short4v o4;
#pragma unroll
        for (int r = 0; r < 4; ++r) o4[r] = f2bf(OB[dt][r] * invB);
        *(short4v*)(cb + dt * 16) = o4;
      }
    }
  }
}

// --------------------------------------------------
extern "C" void kernel_launch(void* const* d_in, const int* in_sizes, int n_in,
                              void* d_out, int out_size, void* d_ws, size_t ws_size,
                              hipStream_t stream) {
  const float* x  = (const float*)d_in[0];
  const float* Wq = (const float*)d_in[1];
  const float* Wk = (const float*)d_in[2];
  const float* Wv = (const float*)d_in[3];
  const float* Wo = (const float*)d_in[4];
  float* out = (float*)d_out;

  // bf16 workspace (72 MB):
  //   xb [8M]  : x bf16; dead after gemm<0> -> reused as ctx
  //   Wt [4x1M]: transposed weights
  //   Qb,Kb [8M each] : projections [bh][t][64]
  //   Vt [8M]  : V^T [bh][64][t]  (written directly by gemm<0> epilogue)
  short* ws  = (short*)d_ws;
  short* xb  = ws;
  short* Wt  = ws + 8388608;
  short* Qb  = Wt + 4 * 1048576;
  short* Kb  = Qb + 8388608;
  short* Vt  = Kb + 8388608;
  short* ctx = xb;

  cvt_kernel<<<dim3(32, 32, 5), dim3(32, 8), 0, stream>>>(Wq, Wk, Wv, Wo, Wt, x, xb);
  gemm_bt<0><<<dim3(64, 24), 256, 0, stream>>>(xb, Wt, Qb, Vt, nullptr, 1024);
  attn_kernel<<<dim3(8, 64), 256, 0, stream>>>(Qb, Kb, Vt, ctx);
  gemm_bt<1><<<dim3(64, 8), 256, 0, stream>>>(ctx, Wt + 3 * 1048576, nullptr, nullptr, out, 1024);
}

// Round 3
// 242.827 us; speedup vs baseline: 1.0904x; 1.0585x over previous
//
#include <hip/hip_runtime.h>

// ---------------------------------------------------------------------------
// MHA: out = softmax_causal((xWq)(xWk)^T / sqrt(64)) (xWv) Wo
// B=4 T=2048 D=1024 H=16 Dh=64.  All matmuls in bf16 MFMA (fp32 accum).
// R11: attn is latency-bound (MFMA 20%/VALU 34%/occ 19%, conflicts proven
// off-critical-path in R10).  Restructure: 8-wave blocks, one 256-row
// q-band per block (waves share one K/V staging -> staging units 136->72
// per bh), P chunk-interleaved (QK^T+PV per 32-col chunk) so Ps = 2.5KB/wave.
// LDS 59.25KB -> 2 blocks/CU = 16 waves/CU (2x TLP).  R10 swizzle reverted
// (null result); strides 72/136/40 are naturally bank-clean (odd 16B-block
// stride, same pattern as the measured-clean Ks).
// ---------------------------------------------------------------------------

typedef short  short8  __attribute__((ext_vector_type(8)));
typedef short  short4v __attribute__((ext_vector_type(4)));
typedef float  floatx4 __attribute__((ext_vector_type(4)));
typedef unsigned uint2v __attribute__((ext_vector_type(2)));

#define T_SZ 2048
#define DM   1024

// 0.125 (Dh^-0.5) * log2(e): softmax in base-2 domain -> native v_exp_f32
#define QSCALE 0.18033688011112042f

__device__ __forceinline__ short f2bf(float f) {
  unsigned u = __float_as_uint(f);
  u += 0x7fffu + ((u >> 16) & 1u);        // RNE
  return (short)(u >> 16);
}

#if defined(__has_builtin) && __has_builtin(__builtin_amdgcn_cvt_pk_bf16_f32)
typedef __bf16 bf16x2_t __attribute__((ext_vector_type(2)));
__device__ __forceinline__ unsigned pack_bf(float lo, float hi) {   // 1 VALU op
  return __builtin_bit_cast(unsigned, __builtin_amdgcn_cvt_pk_bf16_f32(lo, hi));
}
#else
__device__ __forceinline__ unsigned pack_bf(float lo, float hi) {   // 3 VALU ops
  return __builtin_amdgcn_perm(__float_as_uint(hi) + 0x8000u,
                               __float_as_uint(lo) + 0x8000u, 0x07060302u);
}
#endif

#if defined(__has_builtin) && __has_builtin(__builtin_amdgcn_exp2f)
__device__ __forceinline__ float fexp2(float x) { return __builtin_amdgcn_exp2f(x); }
#else
__device__ __forceinline__ float fexp2(float x) { return exp2f(x); }
#endif

__device__ __forceinline__ void gll16(const void* g, void* l) {
  __builtin_amdgcn_global_load_lds((const __attribute__((address_space(1))) void*)g,
                                   (__attribute__((address_space(3))) void*)l, 16, 0, 0);
}

// -------------------------------------------------- converts, one launch
// z in [0,4): W[z] fp32 [K,N] -> bf16 W^T [N,K]   (grid x,y = 32,32; block 32x8)
// z == 4   : x fp32 -> bf16 flat
__global__ void cvt_kernel(const float* __restrict__ s0, const float* __restrict__ s1,
                           const float* __restrict__ s2, const float* __restrict__ s3,
                           short* __restrict__ dst,
                           const float* __restrict__ x, short* __restrict__ xb) {
  const int tx = threadIdx.x, ty = threadIdx.y;       // block (32,8)
  if (blockIdx.z == 4) {                              // ---- x -> bf16
    const int tid = ty * 32 + tx;
    const int blk = blockIdx.y * 32 + blockIdx.x;     // 0..1023
    int i = (blk * 256 + tid) * 4;
#pragma unroll
    for (int j = 0; j < 8; ++j) {
      const float4 v = *(const float4*)(x + i);
      short4v o;
      o.x = f2bf(v.x); o.y = f2bf(v.y); o.z = f2bf(v.z); o.w = f2bf(v.w);
      *(short4v*)(xb + i) = o;
      i += 1048576;
    }
    return;
  }
  const float* srcs[4] = {s0, s1, s2, s3};
  const float* src = srcs[blockIdx.z];
  short* d = dst + (size_t)blockIdx.z * 1048576;
  __shared__ float tile[32][33];
  const int n_base = blockIdx.x * 32, k_base = blockIdx.y * 32;
#pragma unroll
  for (int j = 0; j < 4; ++j)
    tile[ty + j * 8][tx] = src[(size_t)(k_base + ty + j * 8) * 1024 + n_base + tx];
  __syncthreads();
#pragma unroll
  for (int j = 0; j < 4; ++j)
    d[(size_t)(n_base + ty + j * 8) * 1024 + k_base + tx] = f2bf(tile[tx][ty + j * 8]);
}

// -------------------------------------------------- GEMM  C = A[M,K] * Bt[N,K]^T
// XCD-swizzled block mapping: lid%8 = XCD; each XCD owns 8 m-stripes (2 MB of
// A -> L2-resident) and walks n sequentially (B-tile hot).  gridDim.x must be 64.
// MODE 0: QKV epilogue.  Q (wsel0, scaled) / K (wsel1) -> bf16 [bh][t][64];
//         V (wsel2) -> V^T bf16 [bh][64][t] (transpose fused, 8B packed stores)
// MODE 1: fp32 row-major epilogue -> d_out
template <int MODE>
__global__ void gemm_bt(const short* __restrict__ A, const short* __restrict__ Bt,
                        short* __restrict__ obf, short* __restrict__ vt,
                        float* __restrict__ of, int K) {
  __shared__ short As[128 * 32];
  __shared__ short Bs[128 * 32];
  const int tid  = threadIdx.x;
  const int w    = tid >> 6, lane = tid & 63;
  const int quad = lane >> 4, l15 = lane & 15;
  const int wr   = w >> 1, wc = w & 1;
  const int lid  = (int)blockIdx.y * 64 + (int)blockIdx.x;
  const int m0   = (((lid & 7) + 8 * ((lid >> 3) & 7))) * 128;
  const int n0   = (lid >> 6) * 128;
  const int arow = tid >> 2, apart = tid & 3;

  floatx4 acc[4][4] = {};

  for (int kk = 0; kk < K; kk += 32) {
    gll16(A  + (size_t)(m0 + arow) * K      + kk + apart * 8, &As[tid * 8]);
    gll16(A  + (size_t)(m0 + 64 + arow) * K + kk + apart * 8, &As[(256 + tid) * 8]);
    gll16(Bt + (size_t)(n0 + arow) * K      + kk + apart * 8, &Bs[tid * 8]);
    gll16(Bt + (size_t)(n0 + 64 + arow) * K + kk + apart * 8, &Bs[(256 + tid) * 8]);
    __syncthreads();
    short8 af[4], bfr[4];
#pragma unroll
    for (int i = 0; i < 4; ++i)
      af[i] = *(const short8*)&As[(wr * 64 + i * 16 + l15) * 32 + quad * 8];
#pragma unroll
    for (int j = 0; j < 4; ++j)
      bfr[j] = *(const short8*)&Bs[(wc * 64 + j * 16 + l15) * 32 + quad * 8];
#pragma unroll
    for (int i = 0; i < 4; ++i)
#pragma unroll
      for (int j = 0; j < 4; ++j)
        acc[i][j] = __builtin_amdgcn_mfma_f32_16x16x32_bf16(af[i], bfr[j], acc[i][j], 0, 0, 0);
    __syncthreads();
  }

  if (MODE == 0) {
    const int wsel = n0 >> 10;
    const int ncol0 = (n0 & 1023) + wc * 64;
    if (wsel < 2) {
      const float scale = (wsel == 0) ? QSCALE : 1.0f;
      short* outw = obf + (size_t)wsel * (64u * 2048u * 64u);
#pragma unroll
      for (int i = 0; i < 4; ++i) {
        const int row0 = m0 + wr * 64 + i * 16 + quad * 4;
#pragma unroll
        for (int j = 0; j < 4; ++j) {
          const int col = ncol0 + j * 16 + l15;
          const int h = col >> 6, d = col & 63;
#pragma unroll
          for (int r = 0; r < 4; ++r) {
            const int rg = row0 + r;
            const int b = rg >> 11, t = rg & 2047;
            outw[(((size_t)(b * 16 + h) * 2048 + t) << 6) + d] = f2bf(acc[i][j][r] * scale);
          }
        }
      }
    } else {                         // V -> V^T [bh][d][2048], 4 consecutive t per lane
#pragma unroll
      for (int i = 0; i < 4; ++i) {
        const int row0 = m0 + wr * 64 + i * 16 + quad * 4;   // t base (mult of 4)
        const int b = row0 >> 11, t = row0 & 2047;
#pragma unroll
        for (int j = 0; j < 4; ++j) {
          const int col = ncol0 + j * 16 + l15;
          const int h = col >> 6, d = col & 63;
          short4v pv;
#pragma unroll
          for (int r = 0; r < 4; ++r) pv[r] = f2bf(acc[i][j][r]);
          *(short4v*)(vt + (((size_t)(b * 16 + h) * 64 + d) << 11) + t) = pv;
        }
      }
    }
  } else {
#pragma unroll
    for (int i = 0; i < 4; ++i) {
      const int row0 = m0 + wr * 64 + i * 16 + quad * 4;
#pragma unroll
      for (int j = 0; j < 4; ++j) {
        const int col = n0 + wc * 64 + j * 16 + l15;
#pragma unroll
        for (int r = 0; r < 4; ++r)
          of[(size_t)(row0 + r) * 1024 + col] = acc[i][j][r];
      }
    }
  }
}

// -------------------------------------------------- flash attention (causal, transposed)
// grid (8, 64), block 512 (8 waves).  bh = bx + 8*(by&7) -> one XCD per bh
// group (K/V L2-local).  Block = one 256-row q-band (qb), waves 0..7 own
// 32 q rows each (strips A/B of 16; kf/vf frag reads feed both strips).
// All 8 waves share one staged K/V tile -> staging halved vs 4-wave pairs.
// P is chunk-interleaved: for each 32-col chunk c, QK^T(mt=2c,2c+1) -> exp2
// -> P in per-wave LDS [32][40] -> PV(c) immediately.  l = softmax denom
// via MFMA against ones-row 64 of Vs.  2 blocks/CU (59.25 KB LDS), CU-pair
// balance: co-resident blocks have qb and 7-qb (durations sum const).
__global__ __launch_bounds__(512, 4) void attn_kernel(
    const short* __restrict__ Qg, const short* __restrict__ Kg,
    const short* __restrict__ Vt, short* __restrict__ ctx) {
  __shared__ short Ks[128 * 72];       // [t_k][d]                    18.00 KB
  __shared__ short Vs[80 * 136];       // [d][t_k], row 64 = ones     21.25 KB
  __shared__ short Ps[8 * 32 * 40];    // per-wave [q(32)][k(32)+pad] 20.00 KB

  const int tid  = threadIdx.x;
  const int w    = tid >> 6, lane = tid & 63;
  const int quad = lane >> 4, l15 = lane & 15;
  const int bh = (int)blockIdx.x + 8 * ((int)blockIdx.y & 7);
  const int g  = (int)blockIdx.y >> 3;
  const int qb = (g < 4) ? (7 - g) : (g - 4);   // CU pairs get qb + (7-qb)
  const int b  = bh >> 4, h = bh & 15;

  const size_t base = (size_t)bh * (T_SZ * 64);
  const short* Qb  = Qg + base;
  const short* Kb  = Kg + base;
  const short* Vtb = Vt + base;
  short* Pw = &Ps[w * 1280];

  // staging (512 thr): K row skr, 32B at col skp; V row svr, 32B at col svp
  const int skr = tid >> 2, skp = (tid & 3) * 16;
  const int svr = tid >> 3, svp = (tid & 7) * 16;

  // init Vs rows 64..79: row 64 = 1.0 (l-reduction), 65..79 = 0
  if (tid < 256) {
    const int rr = 64 + (tid >> 4), cb = (tid & 15) * 8;
    const short vv = (tid < 16) ? (short)0x3F80 : (short)0;
    short8 fill;
#pragma unroll
    for (int j = 0; j < 8; ++j) fill[j] = vv;
    *(short8*)&Vs[rr * 136 + cb] = fill;
  }

  const int rowA = qb * 256 + w * 32;          // strip A (16 q), strip B = +16
  const int rowB = rowA + 16;
  const int ktmax = 2 * qb + 2;

  const short8 qA0 = *(const short8*)(Qb + (size_t)(rowA + l15) * 64 + quad * 8);
  const short8 qA1 = *(const short8*)(Qb + (size_t)(rowA + l15) * 64 + 32 + quad * 8);
  const short8 qB0 = *(const short8*)(Qb + (size_t)(rowB + l15) * 64 + quad * 8);
  const short8 qB1 = *(const short8*)(Qb + (size_t)(rowB + l15) * 64 + 32 + quad * 8);

  floatx4 OA[4] = {}, OB[4] = {};
  floatx4 O5A = {}, O5B = {};                  // row: l in quad0/reg0

  // preload tile 0 into registers
  short8 kR[2], vR[2];
  kR[0] = *(const short8*)(Kb + (size_t)skr * 64 + skp);
  kR[1] = *(const short8*)(Kb + (size_t)skr * 64 + skp + 8);
  vR[0] = *(const short8*)(Vtb + (size_t)svr * 2048 + svp);
  vR[1] = *(const short8*)(Vtb + (size_t)svr * 2048 + svp + 8);

  for (int kt = 0; kt < ktmax; ++kt) {
    const int k0 = kt << 7;
    __syncthreads();                           // prior tile's LDS reads done
    *(short8*)&Ks[skr * 72 + skp]     = kR[0];
    *(short8*)&Ks[skr * 72 + skp + 8] = kR[1];
    *(short8*)&Vs[svr * 136 + svp]     = vR[0];
    *(short8*)&Vs[svr * 136 + svp + 8] = vR[1];
    if (kt + 1 < ktmax) {                      // prefetch next tile
      const int kn = (kt + 1) << 7;
      kR[0] = *(const short8*)(Kb + (size_t)(kn + skr) * 64 + skp);
      kR[1] = *(const short8*)(Kb + (size_t)(kn + skr) * 64 + skp + 8);
      vR[0] = *(const short8*)(Vtb + (size_t)svr * 2048 + kn + svp);
      vR[1] = *(const short8*)(Vtb + (size_t)svr * 2048 + kn + svp + 8);
    }
    __syncthreads();                           // staged LDS visible

    const int dkA = rowA - k0;                 // wave-uniform
    if (dkA < 0) continue;                     // tail: wave idle, barriers done
    const int dkB = dkA + 16;
    const int limA = dkA + l15, limB = limA + 16;
    const int naA = min(8, (dkA >> 4) + 1), nchA = (naA + 1) >> 1;
    const int naB = min(8, (dkB >> 4) + 1), nchB = (naB + 1) >> 1;

#pragma unroll
    for (int c = 0; c < 4; ++c) {
      if (c < nchB) {
        // ---- QK^T for the chunk's two 16-col tiles -> P LDS
#pragma unroll
        for (int mm = 0; mm < 2; ++mm) {
          const int mt = 2 * c + mm;
          const int pa = l15 * 40 + mm * 16 + quad * 4;          // strip A
          const int pb = (16 + l15) * 40 + mm * 16 + quad * 4;   // strip B
          const bool aB = (mt * 16 < dkB + 16);
          const bool aA = (mt * 16 < dkA + 16);
          if (aB) {
            const short8 kf0 = *(const short8*)&Ks[(mt * 16 + l15) * 72 + quad * 8];
            const short8 kf1 = *(const short8*)&Ks[(mt * 16 + l15) * 72 + 32 + quad * 8];
            {                                  // ---- strip B
              floatx4 s = {};
              s = __builtin_amdgcn_mfma_f32_16x16x32_bf16(kf0, qB0, s, 0, 0, 0);
              s = __builtin_amdgcn_mfma_f32_16x16x32_bf16(kf1, qB1, s, 0, 0, 0);
              if (mt * 16 + 15 > dkB) {
#pragma unroll
                for (int r = 0; r < 4; ++r)
                  if (mt * 16 + quad * 4 + r > limB) s[r] = -1e30f;
              }
              floatx4 e;
#pragma unroll
              for (int r = 0; r < 4; ++r) e[r] = fexp2(s[r]);
              uint2v pd;
              pd.x = pack_bf(e[0], e[1]);
              pd.y = pack_bf(e[2], e[3]);
              *(uint2v*)&Pw[pb] = pd;
            }
            if (c < nchA) {                    // ---- strip A (reuses kf)
              if (aA) {
                floatx4 s = {};
                s = __builtin_amdgcn_mfma_f32_16x16x32_bf16(kf0, qA0, s, 0, 0, 0);
                s = __builtin_amdgcn_mfma_f32_16x16x32_bf16(kf1, qA1, s, 0, 0, 0);
                if (mt * 16 + 15 > dkA) {
#pragma unroll
                  for (int r = 0; r < 4; ++r)
                    if (mt * 16 + quad * 4 + r > limA) s[r] = -1e30f;
                }
                floatx4 e;
#pragma unroll
                for (int r = 0; r < 4; ++r) e[r] = fexp2(s[r]);
                uint2v pd;
                pd.x = pack_bf(e[0], e[1]);
                pd.y = pack_bf(e[2], e[3]);
                *(uint2v*)&Pw[pa] = pd;
              } else {
                uint2v z; z.x = 0; z.y = 0;
                *(uint2v*)&Pw[pa] = z;
              }
            }
          } else {                             // aB false => aA false (mm==1)
            uint2v z; z.x = 0; z.y = 0;
            *(uint2v*)&Pw[pb] = z;
            if (c < nchA) *(uint2v*)&Pw[pa] = z;
          }
        }
        // ---- PV for chunk c
        const int vcol = c * 32 + quad * 8;
        const short8 vfl = *(const short8*)&Vs[(64 + l15) * 136 + vcol];
        short8 vf[4];
#pragma unroll
        for (int dt = 0; dt < 4; ++dt)
          vf[dt] = *(const short8*)&Vs[(dt * 16 + l15) * 136 + vcol];
        const short8 pfB = *(const short8*)&Pw[(16 + l15) * 40 + quad * 8];
#pragma unroll
        for (int dt = 0; dt < 4; ++dt)
          OB[dt] = __builtin_amdgcn_mfma_f32_16x16x32_bf16(vf[dt], pfB, OB[dt], 0, 0, 0);
        O5B = __builtin_amdgcn_mfma_f32_16x16x32_bf16(vfl, pfB, O5B, 0, 0, 0);
        if (c < nchA) {                        // reuses vf/vfl
          const short8 pfA = *(const short8*)&Pw[l15 * 40 + quad * 8];
#pragma unroll
          for (int dt = 0; dt < 4; ++dt)
            OA[dt] = __builtin_amdgcn_mfma_f32_16x16x32_bf16(vf[dt], pfA, OA[dt], 0, 0, 0);
          O5A = __builtin_amdgcn_mfma_f32_16x16x32_bf16(vfl, pfA, O5A, 0, 0, 0);
        }
      }
    }
  }

  // epilogue: l = O5[0] of quad0 lane l15 (C-layout row 0 = ones-row d=64)
  {
    const float lA = __shfl(O5A[0], l15);
    const float invA = 1.0f / lA;
    const int t = rowA + l15;
    short* cb = ctx + (((size_t)(b * T_SZ + t)) << 10) + h * 64 + quad * 4;
#pragma unroll
    for (int dt = 0; dt < 4; ++dt) {
      short4v o4;
#pragma unroll
      for (int r = 0; r < 4; ++r) o4[r] = f2bf(OA[dt][r] * invA);
      *(short4v*)(cb + dt * 16) = o4;
    }
  }
  {
    const float lB = __shfl(O5B[0], l15);
    const float invB = 1.0f / lB;
    const int t = rowB + l15;
    short* cb = ctx + (((size_t)(b * T_SZ + t)) << 10) + h * 64 + quad * 4;
#pragma unroll
    for (int dt = 0; dt < 4; ++dt) {
      short4v o4;
#pragma unroll
      for (int r = 0; r < 4; ++r) o4[r] = f2bf(OB[dt][r] * invB);
      *(short4v*)(cb + dt * 16) = o4;
    }
  }
}

// --------------------------------------------------
extern "C" void kernel_launch(void* const* d_in, const int* in_sizes, int n_in,
                              void* d_out, int out_size, void* d_ws, size_t ws_size,
                              hipStream_t stream) {
  const float* x  = (const float*)d_in[0];
  const float* Wq = (const float*)d_in[1];
  const float* Wk = (const float*)d_in[2];
  const float* Wv = (const float*)d_in[3];
  const float* Wo = (const float*)d_in[4];
  float* out = (float*)d_out;

  // bf16 workspace (72 MB):
  //   xb [8M]  : x bf16; dead after gemm<0> -> reused as ctx
  //   Wt [4x1M]: transposed weights
  //   Qb,Kb [8M each] : projections [bh][t][64]
  //   Vt [8M]  : V^T [bh][64][t]  (written directly by gemm<0> epilogue)
  short* ws  = (short*)d_ws;
  short* xb  = ws;
  short* Wt  = ws + 8388608;
  short* Qb  = Wt + 4 * 1048576;
  short* Kb  = Qb + 8388608;
  short* Vt  = Kb + 8388608;
  short* ctx = xb;

  cvt_kernel<<<dim3(32, 32, 5), dim3(32, 8), 0, stream>>>(Wq, Wk, Wv, Wo, Wt, x, xb);
  gemm_bt<0><<<dim3(64, 24), 256, 0, stream>>>(xb, Wt, Qb, Vt, nullptr, 1024);
  attn_kernel<<<dim3(8, 64), 512, 0, stream>>>(Qb, Kb, Vt, ctx);
  gemm_bt<1><<<dim3(64, 8), 256, 0, stream>>>(ctx, Wt + 3 * 1048576, nullptr, nullptr, out, 1024);
}

// Round 4
// 241.144 us; speedup vs baseline: 1.0980x; 1.0070x over previous
//
#include <hip/hip_runtime.h>

// ---------------------------------------------------------------------------
// MHA: out = softmax_causal((xWq)(xWk)^T / sqrt(64)) (xWv) Wo
// B=4 T=2048 D=1024 H=16 Dh=64.  All matmuls in bf16 MFMA (fp32 accum).
// R12: QKV as C^T = Wt * xb^T on the 8-phase BK=64 schedule.  R1's 8-phase
// failed on (a) 384 blocks = 1.5 dispatch rounds and (b) exposed 2B-scatter
// epilogue at 1 block/CU.  Fix: BM=128(W-rows) x BN=256(tokens) -> 768
// blocks = 3.0 clean rounds; transposed output puts head-dim on quad/r so
// Q/K stores are packed short4v (16/thread, was 128 scalar).
// ---------------------------------------------------------------------------

typedef short  short8  __attribute__((ext_vector_type(8)));
typedef short  short4v __attribute__((ext_vector_type(4)));
typedef float  floatx4 __attribute__((ext_vector_type(4)));
typedef unsigned uint2v __attribute__((ext_vector_type(2)));

#define T_SZ 2048
#define DM   1024

// 0.125 (Dh^-0.5) * log2(e): softmax in base-2 domain -> native v_exp_f32
#define QSCALE 0.18033688011112042f

__device__ __forceinline__ short f2bf(float f) {
  unsigned u = __float_as_uint(f);
  u += 0x7fffu + ((u >> 16) & 1u);        // RNE
  return (short)(u >> 16);
}

#if defined(__has_builtin) && __has_builtin(__builtin_amdgcn_cvt_pk_bf16_f32)
typedef __bf16 bf16x2_t __attribute__((ext_vector_type(2)));
__device__ __forceinline__ unsigned pack_bf(float lo, float hi) {   // 1 VALU op
  return __builtin_bit_cast(unsigned, __builtin_amdgcn_cvt_pk_bf16_f32(lo, hi));
}
#else
__device__ __forceinline__ unsigned pack_bf(float lo, float hi) {   // 3 VALU ops
  return __builtin_amdgcn_perm(__float_as_uint(hi) + 0x8000u,
                               __float_as_uint(lo) + 0x8000u, 0x07060302u);
}
#endif

#if defined(__has_builtin) && __has_builtin(__builtin_amdgcn_exp2f)
__device__ __forceinline__ float fexp2(float x) { return __builtin_amdgcn_exp2f(x); }
#else
__device__ __forceinline__ float fexp2(float x) { return exp2f(x); }
#endif

__device__ __forceinline__ void gll16(const void* g, void* l) {
  __builtin_amdgcn_global_load_lds((const __attribute__((address_space(1))) void*)g,
                                   (__attribute__((address_space(3))) void*)l, 16, 0, 0);
}

#define SBAR() asm volatile("s_barrier" ::: "memory")
#define WLG()  asm volatile("s_waitcnt lgkmcnt(0)" ::: "memory")
#define WV6()  asm volatile("s_waitcnt vmcnt(6)" ::: "memory")
#define WV0()  asm volatile("s_waitcnt vmcnt(0)" ::: "memory")

// -------------------------------------------------- converts, one launch
// z in [0,4): W[z] fp32 [K,N] -> bf16 W^T [N,K]   (grid x,y = 32,32; block 32x8)
// z == 4   : x fp32 -> bf16 flat
__global__ void cvt_kernel(const float* __restrict__ s0, const float* __restrict__ s1,
                           const float* __restrict__ s2, const float* __restrict__ s3,
                           short* __restrict__ dst,
                           const float* __restrict__ x, short* __restrict__ xb) {
  const int tx = threadIdx.x, ty = threadIdx.y;       // block (32,8)
  if (blockIdx.z == 4) {                              // ---- x -> bf16
    const int tid = ty * 32 + tx;
    const int blk = blockIdx.y * 32 + blockIdx.x;     // 0..1023
    int i = (blk * 256 + tid) * 4;
#pragma unroll
    for (int j = 0; j < 8; ++j) {
      const float4 v = *(const float4*)(x + i);
      short4v o;
      o.x = f2bf(v.x); o.y = f2bf(v.y); o.z = f2bf(v.z); o.w = f2bf(v.w);
      *(short4v*)(xb + i) = o;
      i += 1048576;
    }
    return;
  }
  const float* srcs[4] = {s0, s1, s2, s3};
  const float* src = srcs[blockIdx.z];
  short* d = dst + (size_t)blockIdx.z * 1048576;
  __shared__ float tile[32][33];
  const int n_base = blockIdx.x * 32, k_base = blockIdx.y * 32;
#pragma unroll
  for (int j = 0; j < 4; ++j)
    tile[ty + j * 8][tx] = src[(size_t)(k_base + ty + j * 8) * 1024 + n_base + tx];
  __syncthreads();
#pragma unroll
  for (int j = 0; j < 4; ++j)
    d[(size_t)(n_base + ty + j * 8) * 1024 + k_base + tx] = f2bf(tile[tx][ty + j * 8]);
}

// -------------------------------------------------- QKV GEMM, transposed 8-phase
// C^T = Wt[3072,1024] * xb[8192,1024]^T.  512 thr (8 waves, 2M x 4N), BK=64.
// BM=128 (W rows m0), BN=256 (tokens n0).  768 blocks = 3 clean rounds
// @ 1 block/CU (96 KB LDS).  2-slot ring: kt0=2t -> slot0 (phases 1-4),
// kt1=2t+1 -> slot1 (5-8).  Stage units (2 gll16 each): p2:B0h0 p3:B0h1
// p4:A0 -> slot0 for kt+2; p6:B1h0 p7:B1h1 p8:A1 -> slot1 for kt+3.
// vmcnt(6) at p4/p8 (12 outstanding, oldest 6 = the slot about to be read).
// T2 swizzle: LDS[row][pb] = G[row][pb ^ (row&7)] via pre-swizzled source;
// ds_read col-block = (s*4+quad) ^ (l15&7).  Epilogue: C^T rows = qkv col
// (head-dim on quad/r -> packed short4v for Q/K), cols = token.
__global__ __launch_bounds__(512, 2) void gemm_qkvT(
    const short* __restrict__ Wt, const short* __restrict__ xb,
    short* __restrict__ obf, short* __restrict__ vt) {
  __shared__ short As[2 * 128 * 64];   // [slot][128][64]  32 KB (Wt tile)
  __shared__ short Bs[2 * 256 * 64];   // [slot][256][64]  64 KB (x tile)
  const int tid  = threadIdx.x;
  const int w    = tid >> 6, lane = tid & 63;
  const int quad = lane >> 4, l15 = lane & 15;
  const int wr   = w >> 2, wc = w & 3;          // 2 (M=128) x 4 (N=256)
  const int fx   = l15 & 7;
  const int lid  = (int)blockIdx.x;             // 768
  // xcd = lid&7 owns tokens [xcd*1024, +1024) (2 MB xb panel, L2-local),
  // walks W-tiles; n fastest within so the W-tile is reused back-to-back.
  const int xcd  = lid & 7, idx = lid >> 3;     // idx in [0,96)
  const int m0   = (idx >> 2) * 128;            // 24 W-row tiles
  const int n0   = (xcd * 4 + (idx & 3)) * 256; // token tile
  const int srow = tid >> 3;
  const int scol = ((tid & 7) ^ (srow & 7)) * 8;

  const short* Ag = Wt + (size_t)(m0 + srow) * 1024 + scol;
  const short* Bg = xb + (size_t)(n0 + srow) * 1024 + scol;

  floatx4 acc[4][4] = {};
  short8 af[2][2], bf[4][2];

#define STG_A(slot, kb) do { \
    short* _lb = &As[(slot) * 8192 + tid * 8]; \
    gll16(Ag + (kb), _lb); \
    gll16(Ag + (size_t)(64 * 1024) + (kb), _lb + 4096); \
  } while (0)
#define STG_B(slot, h, kb) do { \
    short* _lb = &Bs[(slot) * 16384 + (h) * 8192 + tid * 8]; \
    const short* _gp = Bg + (size_t)(h) * (128 * 1024) + (kb); \
    gll16(_gp, _lb); \
    gll16(_gp + (size_t)(64 * 1024), _lb + 4096); \
  } while (0)
#define LDA2(slot, ih) do { \
    _Pragma("unroll") for (int ii = 0; ii < 2; ++ii) \
    _Pragma("unroll") for (int s = 0; s < 2; ++s) \
      af[ii][s] = *(const short8*)&As[(slot) * 8192 + \
          (wr * 64 + (ih) * 32 + ii * 16 + l15) * 64 + ((s * 4 + quad) ^ fx) * 8]; \
  } while (0)
#define LDB8(slot) do { \
    _Pragma("unroll") for (int j = 0; j < 4; ++j) \
    _Pragma("unroll") for (int s = 0; s < 2; ++s) \
      bf[j][s] = *(const short8*)&Bs[(slot) * 16384 + \
          (wc * 64 + j * 16 + l15) * 64 + ((s * 4 + quad) ^ fx) * 8]; \
  } while (0)
#define MMQ(ih, jh) do { \
    __builtin_amdgcn_s_setprio(1); \
    _Pragma("unroll") for (int ii = 0; ii < 2; ++ii) \
    _Pragma("unroll") for (int jj = 0; jj < 2; ++jj) \
    _Pragma("unroll") for (int s = 0; s < 2; ++s) \
      acc[(ih) * 2 + ii][(jh) * 2 + jj] = __builtin_amdgcn_mfma_f32_16x16x32_bf16( \
          af[ii][s], bf[(jh) * 2 + jj][s], acc[(ih) * 2 + ii][(jh) * 2 + jj], 0, 0, 0); \
    __builtin_amdgcn_s_setprio(0); \
  } while (0)

  // prologue: kt0 -> slot0, kt1 -> slot1 (12 loads); WV6 -> kt0's 6 landed.
  STG_B(0, 0, 0);  STG_B(0, 1, 0);  STG_A(0, 0);
  STG_B(1, 0, 64); STG_B(1, 1, 64); STG_A(1, 64);
  WV6(); SBAR();

  for (int t = 0; t < 8; ++t) {
    const int kn2 = (2 * t + 2) * 64;          // -> slot0
    const int kn3 = (2 * t + 3) * 64;          // -> slot1
    const bool mre = (t < 7);
    // ---- p1: read kt0 frags (i-half0 + all B)
    LDA2(0, 0); LDB8(0);
    SBAR(); WLG(); MMQ(0, 0); SBAR();
    // ---- p2   (slot0-B fully read by p1's trailing barrier)
    if (mre) STG_B(0, 0, kn2);
    SBAR(); MMQ(0, 1); SBAR();
    // ---- p3
    LDA2(0, 1);
    if (mre) STG_B(0, 1, kn2);
    SBAR(); WLG(); MMQ(1, 0); SBAR();
    // ---- p4   (slot0-A read done by p3; wait: slot1 (oldest 6) landed)
    if (mre) { STG_A(0, kn2); WV6(); } else { WV0(); }
    SBAR(); MMQ(1, 1); SBAR();
    // ---- p5: read kt1 frags
    LDA2(1, 0); LDB8(1);
    SBAR(); WLG(); MMQ(0, 0); SBAR();
    // ---- p6
    if (mre) STG_B(1, 0, kn3);
    SBAR(); MMQ(0, 1); SBAR();
    // ---- p7
    LDA2(1, 1);
    if (mre) STG_B(1, 1, kn3);
    SBAR(); WLG(); MMQ(1, 0); SBAR();
    // ---- p8   (wait: next slot0 (oldest 6) landed)
    if (mre) { STG_A(1, kn3); WV6(); }
    SBAR(); MMQ(1, 1); SBAR();
  }

  // ---- epilogue: C^T[m=qkv col][n=token].  4 consecutive qkv-cols per lane
  // on the r axis -> packed stores for Q/K ([bh][t][64]); V scatters 2B
  // ([bh][d][2048]) but only on 1/3 of blocks.
  const int wsel = m0 >> 10;                    // 0=Q 1=K 2=V, uniform/block
  const int nn0  = (m0 & 1023) + wr * 64;
  if (wsel < 2) {
    const float scale = (wsel == 0) ? QSCALE : 1.0f;
    short* outw = obf + (size_t)wsel * (64u * 2048u * 64u);
#pragma unroll
    for (int i = 0; i < 4; ++i) {
      const int nn = nn0 + i * 16 + quad * 4;   // qkv col, mult of 4
      const int h = nn >> 6, d = nn & 63;       // h const across r (d<=60+3)
#pragma unroll
      for (int j = 0; j < 4; ++j) {
        const int tg = n0 + wc * 64 + j * 16 + l15;
        const int b = tg >> 11, tt = tg & 2047;
        short4v o4;
#pragma unroll
        for (int r = 0; r < 4; ++r) o4[r] = f2bf(acc[i][j][r] * scale);
        *(short4v*)(outw + (((size_t)(b * 16 + h) * 2048 + tt) << 6) + d) = o4;
      }
    }
  } else {
#pragma unroll
    for (int i = 0; i < 4; ++i) {
      const int nn = nn0 + i * 16 + quad * 4;   // v col in [0,1024)
      const int h = nn >> 6, d = nn & 63;
#pragma unroll
      for (int j = 0; j < 4; ++j) {
        const int tg = n0 + wc * 64 + j * 16 + l15;
        const int b = tg >> 11, tt = tg & 2047;
#pragma unroll
        for (int r = 0; r < 4; ++r)
          vt[(((size_t)(b * 16 + h) * 64 + d + r) << 11) + tt] = f2bf(acc[i][j][r]);
      }
    }
  }
#undef STG_A
#undef STG_B
#undef LDA2
#undef LDB8
#undef MMQ
}

// -------------------------------------------------- GEMM  C = A[M,K] * Bt[N,K]^T
// (retained for the Wo projection, MODE 1)
template <int MODE>
__global__ void gemm_bt(const short* __restrict__ A, const short* __restrict__ Bt,
                        short* __restrict__ obf, short* __restrict__ vt,
                        float* __restrict__ of, int K) {
  __shared__ short As[128 * 32];
  __shared__ short Bs[128 * 32];
  const int tid  = threadIdx.x;
  const int w    = tid >> 6, lane = tid & 63;
  const int quad = lane >> 4, l15 = lane & 15;
  const int wr   = w >> 1, wc = w & 1;
  const int lid  = (int)blockIdx.y * 64 + (int)blockIdx.x;
  const int m0   = (((lid & 7) + 8 * ((lid >> 3) & 7))) * 128;
  const int n0   = (lid >> 6) * 128;
  const int arow = tid >> 2, apart = tid & 3;

  floatx4 acc[4][4] = {};

  for (int kk = 0; kk < K; kk += 32) {
    gll16(A  + (size_t)(m0 + arow) * K      + kk + apart * 8, &As[tid * 8]);
    gll16(A  + (size_t)(m0 + 64 + arow) * K + kk + apart * 8, &As[(256 + tid) * 8]);
    gll16(Bt + (size_t)(n0 + arow) * K      + kk + apart * 8, &Bs[tid * 8]);
    gll16(Bt + (size_t)(n0 + 64 + arow) * K + kk + apart * 8, &Bs[(256 + tid) * 8]);
    __syncthreads();
    short8 af[4], bfr[4];
#pragma unroll
    for (int i = 0; i < 4; ++i)
      af[i] = *(const short8*)&As[(wr * 64 + i * 16 + l15) * 32 + quad * 8];
#pragma unroll
    for (int j = 0; j < 4; ++j)
      bfr[j] = *(const short8*)&Bs[(wc * 64 + j * 16 + l15) * 32 + quad * 8];
#pragma unroll
    for (int i = 0; i < 4; ++i)
#pragma unroll
      for (int j = 0; j < 4; ++j)
        acc[i][j] = __builtin_amdgcn_mfma_f32_16x16x32_bf16(af[i], bfr[j], acc[i][j], 0, 0, 0);
    __syncthreads();
  }

  if (MODE == 0) {
    const int wsel = n0 >> 10;
    const int ncol0 = (n0 & 1023) + wc * 64;
    if (wsel < 2) {
      const float scale = (wsel == 0) ? QSCALE : 1.0f;
      short* outw = obf + (size_t)wsel * (64u * 2048u * 64u);
#pragma unroll
      for (int i = 0; i < 4; ++i) {
        const int row0 = m0 + wr * 64 + i * 16 + quad * 4;
#pragma unroll
        for (int j = 0; j < 4; ++j) {
          const int col = ncol0 + j * 16 + l15;
          const int h = col >> 6, d = col & 63;
#pragma unroll
          for (int r = 0; r < 4; ++r) {
            const int rg = row0 + r;
            const int b = rg >> 11, t = rg & 2047;
            outw[(((size_t)(b * 16 + h) * 2048 + t) << 6) + d] = f2bf(acc[i][j][r] * scale);
          }
        }
      }
    } else {
#pragma unroll
      for (int i = 0; i < 4; ++i) {
        const int row0 = m0 + wr * 64 + i * 16 + quad * 4;
        const int b = row0 >> 11, t = row0 & 2047;
#pragma unroll
        for (int j = 0; j < 4; ++j) {
          const int col = ncol0 + j * 16 + l15;
          const int h = col >> 6, d = col & 63;
          short4v pv;
#pragma unroll
          for (int r = 0; r < 4; ++r) pv[r] = f2bf(acc[i][j][r]);
          *(short4v*)(vt + (((size_t)(b * 16 + h) * 64 + d) << 11) + t) = pv;
        }
      }
    }
  } else {
#pragma unroll
    for (int i = 0; i < 4; ++i) {
      const int row0 = m0 + wr * 64 + i * 16 + quad * 4;
#pragma unroll
      for (int j = 0; j < 4; ++j) {
        const int col = n0 + wc * 64 + j * 16 + l15;
#pragma unroll
        for (int r = 0; r < 4; ++r)
          of[(size_t)(row0 + r) * 1024 + col] = acc[i][j][r];
      }
    }
  }
}

// -------------------------------------------------- flash attention (causal, transposed)
// grid (8, 64), block 512 (8 waves).  bh = bx + 8*(by&7) -> one XCD per bh
// group (K/V L2-local).  Block = one 256-row q-band (qb), waves 0..7 own
// 32 q rows each (strips A/B of 16; kf/vf frag reads feed both strips).
// All 8 waves share one staged K/V tile.  P chunk-interleaved (QK^T+PV per
// 32-col chunk), Ps = 2.5 KB/wave.  59.25 KB LDS -> 2 blocks/CU = 16
// waves/CU.  CU-pair balance: co-resident blocks get qb and 7-qb.
__global__ __launch_bounds__(512, 4) void attn_kernel(
    const short* __restrict__ Qg, const short* __restrict__ Kg,
    const short* __restrict__ Vt, short* __restrict__ ctx) {
  __shared__ short Ks[128 * 72];       // [t_k][d]                    18.00 KB
  __shared__ short Vs[80 * 136];       // [d][t_k], row 64 = ones     21.25 KB
  __shared__ short Ps[8 * 32 * 40];    // per-wave [q(32)][k(32)+pad] 20.00 KB

  const int tid  = threadIdx.x;
  const int w    = tid >> 6, lane = tid & 63;
  const int quad = lane >> 4, l15 = lane & 15;
  const int bh = (int)blockIdx.x + 8 * ((int)blockIdx.y & 7);
  const int g  = (int)blockIdx.y >> 3;
  const int qb = (g < 4) ? (7 - g) : (g - 4);   // CU pairs get qb + (7-qb)
  const int b  = bh >> 4, h = bh & 15;

  const size_t base = (size_t)bh * (T_SZ * 64);
  const short* Qb  = Qg + base;
  const short* Kb  = Kg + base;
  const short* Vtb = Vt + base;
  short* Pw = &Ps[w * 1280];

  // staging (512 thr): K row skr, 32B at col skp; V row svr, 32B at col svp
  const int skr = tid >> 2, skp = (tid & 3) * 16;
  const int svr = tid >> 3, svp = (tid & 7) * 16;

  // init Vs rows 64..79: row 64 = 1.0 (l-reduction), 65..79 = 0
  if (tid < 256) {
    const int rr = 64 + (tid >> 4), cb = (tid & 15) * 8;
    const short vv = (tid < 16) ? (short)0x3F80 : (short)0;
    short8 fill;
#pragma unroll
    for (int j = 0; j < 8; ++j) fill[j] = vv;
    *(short8*)&Vs[rr * 136 + cb] = fill;
  }

  const int rowA = qb * 256 + w * 32;          // strip A (16 q), strip B = +16
  const int rowB = rowA + 16;
  const int ktmax = 2 * qb + 2;

  const short8 qA0 = *(const short8*)(Qb + (size_t)(rowA + l15) * 64 + quad * 8);
  const short8 qA1 = *(const short8*)(Qb + (size_t)(rowA + l15) * 64 + 32 + quad * 8);
  const short8 qB0 = *(const short8*)(Qb + (size_t)(rowB + l15) * 64 + quad * 8);
  const short8 qB1 = *(const short8*)(Qb + (size_t)(rowB + l15) * 64 + 32 + quad * 8);

  floatx4 OA[4] = {}, OB[4] = {};
  floatx4 O5A = {}, O5B = {};                  // row: l in quad0/reg0

  // preload tile 0 into registers
  short8 kR[2], vR[2];
  kR[0] = *(const short8*)(Kb + (size_t)skr * 64 + skp);
  kR[1] = *(const short8*)(Kb + (size_t)skr * 64 + skp + 8);
  vR[0] = *(const short8*)(Vtb + (size_t)svr * 2048 + svp);
  vR[1] = *(const short8*)(Vtb + (size_t)svr * 2048 + svp + 8);

  for (int kt = 0; kt < ktmax; ++kt) {
    const int k0 = kt << 7;
    __syncthreads();                           // prior tile's LDS reads done
    *(short8*)&Ks[skr * 72 + skp]     = kR[0];
    *(short8*)&Ks[skr * 72 + skp + 8] = kR[1];
    *(short8*)&Vs[svr * 136 + svp]     = vR[0];
    *(short8*)&Vs[svr * 136 + svp + 8] = vR[1];
    if (kt + 1 < ktmax) {                      // prefetch next tile
      const int kn = (kt + 1) << 7;
      kR[0] = *(const short8*)(Kb + (size_t)(kn + skr) * 64 + skp);
      kR[1] = *(const short8*)(Kb + (size_t)(kn + skr) * 64 + skp + 8);
      vR[0] = *(const short8*)(Vtb + (size_t)svr * 2048 + kn + svp);
      vR[1] = *(const short8*)(Vtb + (size_t)svr * 2048 + kn + svp + 8);
    }
    __syncthreads();                           // staged LDS visible

    const int dkA = rowA - k0;                 // wave-uniform
    if (dkA < 0) continue;                     // tail: wave idle, barriers done
    const int dkB = dkA + 16;
    const int limA = dkA + l15, limB = limA + 16;
    const int naA = min(8, (dkA >> 4) + 1), nchA = (naA + 1) >> 1;
    const int naB = min(8, (dkB >> 4) + 1), nchB = (naB + 1) >> 1;

#pragma unroll
    for (int c = 0; c < 4; ++c) {
      if (c < nchB) {
        // ---- QK^T for the chunk's two 16-col tiles -> P LDS
#pragma unroll
        for (int mm = 0; mm < 2; ++mm) {
          const int mt = 2 * c + mm;
          const int pa = l15 * 40 + mm * 16 + quad * 4;          // strip A
          const int pb = (16 + l15) * 40 + mm * 16 + quad * 4;   // strip B
          const bool aB = (mt * 16 < dkB + 16);
          const bool aA = (mt * 16 < dkA + 16);
          if (aB) {
            const short8 kf0 = *(const short8*)&Ks[(mt * 16 + l15) * 72 + quad * 8];
            const short8 kf1 = *(const short8*)&Ks[(mt * 16 + l15) * 72 + 32 + quad * 8];
            {                                  // ---- strip B
              floatx4 s = {};
              s = __builtin_amdgcn_mfma_f32_16x16x32_bf16(kf0, qB0, s, 0, 0, 0);
              s = __builtin_amdgcn_mfma_f32_16x16x32_bf16(kf1, qB1, s, 0, 0, 0);
              if (mt * 16 + 15 > dkB) {
#pragma unroll
                for (int r = 0; r < 4; ++r)
                  if (mt * 16 + quad * 4 + r > limB) s[r] = -1e30f;
              }
              floatx4 e;
#pragma unroll
              for (int r = 0; r < 4; ++r) e[r] = fexp2(s[r]);
              uint2v pd;
              pd.x = pack_bf(e[0], e[1]);
              pd.y = pack_bf(e[2], e[3]);
              *(uint2v*)&Pw[pb] = pd;
            }
            if (c < nchA) {                    // ---- strip A (reuses kf)
              if (aA) {
                floatx4 s = {};
                s = __builtin_amdgcn_mfma_f32_16x16x32_bf16(kf0, qA0, s, 0, 0, 0);
                s = __builtin_amdgcn_mfma_f32_16x16x32_bf16(kf1, qA1, s, 0, 0, 0);
                if (mt * 16 + 15 > dkA) {
#pragma unroll
                  for (int r = 0; r < 4; ++r)
                    if (mt * 16 + quad * 4 + r > limA) s[r] = -1e30f;
                }
                floatx4 e;
#pragma unroll
                for (int r = 0; r < 4; ++r) e[r] = fexp2(s[r]);
                uint2v pd;
                pd.x = pack_bf(e[0], e[1]);
                pd.y = pack_bf(e[2], e[3]);
                *(uint2v*)&Pw[pa] = pd;
              } else {
                uint2v z; z.x = 0; z.y = 0;
                *(uint2v*)&Pw[pa] = z;
              }
            }
          } else {                             // aB false => aA false (mm==1)
            uint2v z; z.x = 0; z.y = 0;
            *(uint2v*)&Pw[pb] = z;
            if (c < nchA) *(uint2v*)&Pw[pa] = z;
          }
        }
        // ---- PV for chunk c
        const int vcol = c * 32 + quad * 8;
        const short8 vfl = *(const short8*)&Vs[(64 + l15) * 136 + vcol];
        short8 vf[4];
#pragma unroll
        for (int dt = 0; dt < 4; ++dt)
          vf[dt] = *(const short8*)&Vs[(dt * 16 + l15) * 136 + vcol];
        const short8 pfB = *(const short8*)&Pw[(16 + l15) * 40 + quad * 8];
#pragma unroll
        for (int dt = 0; dt < 4; ++dt)
          OB[dt] = __builtin_amdgcn_mfma_f32_16x16x32_bf16(vf[dt], pfB, OB[dt], 0, 0, 0);
        O5B = __builtin_amdgcn_mfma_f32_16x16x32_bf16(vfl, pfB, O5B, 0, 0, 0);
        if (c < nchA) {                        // reuses vf/vfl
          const short8 pfA = *(const short8*)&Pw[l15 * 40 + quad * 8];
#pragma unroll
          for (int dt = 0; dt < 4; ++dt)
            OA[dt] = __builtin_amdgcn_mfma_f32_16x16x32_bf16(vf[dt], pfA, OA[dt], 0, 0, 0);
          O5A = __builtin_amdgcn_mfma_f32_16x16x32_bf16(vfl, pfA, O5A, 0, 0, 0);
        }
      }
    }
  }

  // epilogue: l = O5[0] of quad0 lane l15 (C-layout row 0 = ones-row d=64)
  {
    const float lA = __shfl(O5A[0], l15);
    const float invA = 1.0f / lA;
    const int t = rowA + l15;
    short* cb = ctx + (((size_t)(b * T_SZ + t)) << 10) + h * 64 + quad * 4;
#pragma unroll
    for (int dt = 0; dt < 4; ++dt) {
      short4v o4;
#pragma unroll
      for (int r = 0; r < 4; ++r) o4[r] = f2bf(OA[dt][r] * invA);
      *(short4v*)(cb + dt * 16) = o4;
    }
  }
  {
    const float lB = __shfl(O5B[0], l15);
    const float invB = 1.0f / lB;
    const int t = rowB + l15;
    short* cb = ctx + (((size_t)(b * T_SZ + t)) << 10) + h * 64 + quad * 4;
#pragma unroll
    for (int dt = 0; dt < 4; ++dt) {
      short4v o4;
#pragma unroll
      for (int r = 0; r < 4; ++r) o4[r] = f2bf(OB[dt][r] * invB);
      *(short4v*)(cb + dt * 16) = o4;
    }
  }
}

// --------------------------------------------------
extern "C" void kernel_launch(void* const* d_in, const int* in_sizes, int n_in,
                              void* d_out, int out_size, void* d_ws, size_t ws_size,
                              hipStream_t stream) {
  const float* x  = (const float*)d_in[0];
  const float* Wq = (const float*)d_in[1];
  const float* Wk = (const float*)d_in[2];
  const float* Wv = (const float*)d_in[3];
  const float* Wo = (const float*)d_in[4];
  float* out = (float*)d_out;

  // bf16 workspace (72 MB):
  //   xb [8M]  : x bf16; dead after gemm_qkvT -> reused as ctx
  //   Wt [4x1M]: transposed weights
  //   Qb,Kb [8M each] : projections [bh][t][64]
  //   Vt [8M]  : V^T [bh][64][t]  (written directly by gemm_qkvT epilogue)
  short* ws  = (short*)d_ws;
  short* xb  = ws;
  short* Wt  = ws + 8388608;
  short* Qb  = Wt + 4 * 1048576;
  short* Kb  = Qb + 8388608;
  short* Vt  = Kb + 8388608;
  short* ctx = xb;

  cvt_kernel<<<dim3(32, 32, 5), dim3(32, 8), 0, stream>>>(Wq, Wk, Wv, Wo, Wt, x, xb);
  gemm_qkvT<<<dim3(768), 512, 0, stream>>>(Wt, xb, Qb, Vt);
  attn_kernel<<<dim3(8, 64), 512, 0, stream>>>(Qb, Kb, Vt, ctx);
  gemm_bt<1><<<dim3(64, 8), 256, 0, stream>>>(ctx, Wt + 3 * 1048576, nullptr, nullptr, out, 1024);
}

// Round 5
// 236.696 us; speedup vs baseline: 1.1186x; 1.0188x over previous
//
#include <hip/hip_runtime.h>

// ---------------------------------------------------------------------------
// MHA: out = softmax_causal((xWq)(xWk)^T / sqrt(64)) (xWv) Wo
// B=4 T=2048 D=1024 H=16 Dh=64.  All matmuls in bf16 MFMA (fp32 accum).
// R13: phase analysis showed phase TIME (~350ns) is overhead-dominated and
// independent of MFMA count -> merge 8 phases into 4 phases x 16 MFMA.
// p1: read ALL slot0 frags (16 b128), MFMA M-half0; p2: MFMA M-half1 (no
// reads) + stage slot0-next (6 gll16) + vmcnt(6); p3/p4 mirror slot1.
// Invariant: stage-into-slot only in the phase after full-read (behind
// WLG+barrier); WV6 after each stage (12 outstanding -> older slot landed).
// Same template drives Wo (M=1024 -> 256 blocks = 1.0 round, float4 fp32
// epilogue) -> gemm_bt retired.
// ---------------------------------------------------------------------------

typedef short  short8  __attribute__((ext_vector_type(8)));
typedef short  short4v __attribute__((ext_vector_type(4)));
typedef float  floatx4 __attribute__((ext_vector_type(4)));
typedef unsigned uint2v __attribute__((ext_vector_type(2)));

#define T_SZ 2048
#define DM   1024

// 0.125 (Dh^-0.5) * log2(e): softmax in base-2 domain -> native v_exp_f32
#define QSCALE 0.18033688011112042f

__device__ __forceinline__ short f2bf(float f) {
  unsigned u = __float_as_uint(f);
  u += 0x7fffu + ((u >> 16) & 1u);        // RNE
  return (short)(u >> 16);
}

#if defined(__has_builtin) && __has_builtin(__builtin_amdgcn_cvt_pk_bf16_f32)
typedef __bf16 bf16x2_t __attribute__((ext_vector_type(2)));
__device__ __forceinline__ unsigned pack_bf(float lo, float hi) {   // 1 VALU op
  return __builtin_bit_cast(unsigned, __builtin_amdgcn_cvt_pk_bf16_f32(lo, hi));
}
#else
__device__ __forceinline__ unsigned pack_bf(float lo, float hi) {   // 3 VALU ops
  return __builtin_amdgcn_perm(__float_as_uint(hi) + 0x8000u,
                               __float_as_uint(lo) + 0x8000u, 0x07060302u);
}
#endif

#if defined(__has_builtin) && __has_builtin(__builtin_amdgcn_exp2f)
__device__ __forceinline__ float fexp2(float x) { return __builtin_amdgcn_exp2f(x); }
#else
__device__ __forceinline__ float fexp2(float x) { return exp2f(x); }
#endif

__device__ __forceinline__ void gll16(const void* g, void* l) {
  __builtin_amdgcn_global_load_lds((const __attribute__((address_space(1))) void*)g,
                                   (__attribute__((address_space(3))) void*)l, 16, 0, 0);
}

#define SBAR() asm volatile("s_barrier" ::: "memory")
#define WLG()  asm volatile("s_waitcnt lgkmcnt(0)" ::: "memory")
#define WV6()  asm volatile("s_waitcnt vmcnt(6)" ::: "memory")
#define WV0()  asm volatile("s_waitcnt vmcnt(0)" ::: "memory")

// -------------------------------------------------- converts, one launch
// z in [0,4): W[z] fp32 [K,N] -> bf16 W^T [N,K]   (grid x,y = 32,32; block 32x8)
// z == 4   : x fp32 -> bf16 flat
__global__ void cvt_kernel(const float* __restrict__ s0, const float* __restrict__ s1,
                           const float* __restrict__ s2, const float* __restrict__ s3,
                           short* __restrict__ dst,
                           const float* __restrict__ x, short* __restrict__ xb) {
  const int tx = threadIdx.x, ty = threadIdx.y;       // block (32,8)
  if (blockIdx.z == 4) {                              // ---- x -> bf16
    const int tid = ty * 32 + tx;
    const int blk = blockIdx.y * 32 + blockIdx.x;     // 0..1023
    int i = (blk * 256 + tid) * 4;
#pragma unroll
    for (int j = 0; j < 8; ++j) {
      const float4 v = *(const float4*)(x + i);
      short4v o;
      o.x = f2bf(v.x); o.y = f2bf(v.y); o.z = f2bf(v.z); o.w = f2bf(v.w);
      *(short4v*)(xb + i) = o;
      i += 1048576;
    }
    return;
  }
  const float* srcs[4] = {s0, s1, s2, s3};
  const float* src = srcs[blockIdx.z];
  short* d = dst + (size_t)blockIdx.z * 1048576;
  __shared__ float tile[32][33];
  const int n_base = blockIdx.x * 32, k_base = blockIdx.y * 32;
#pragma unroll
  for (int j = 0; j < 4; ++j)
    tile[ty + j * 8][tx] = src[(size_t)(k_base + ty + j * 8) * 1024 + n_base + tx];
  __syncthreads();
#pragma unroll
  for (int j = 0; j < 4; ++j)
    d[(size_t)(n_base + ty + j * 8) * 1024 + k_base + tx] = f2bf(tile[tx][ty + j * 8]);
}

// -------------------------------------------------- transposed GEMM, 4-phase
// C^T = A[M,1024] * B[N,1024]^T, tile 128(m) x 256(n), BK=64, 512 thr
// (8 waves 2Mx4N, 64x64 each).  2-slot LDS ring; per t-iter (2 K-tiles):
//   p1: ds_read all slot0 frags (16 b128) | MFMA ih=0 (16)
//   p2: stage slot0<-kt+2 (6 gll16) | MFMA ih=1 | WV6
//   p3/p4: same on slot1 (kt+3)
// WV6: 12 outstanding after each stage burst -> drain to 6 = older slot
// landed, read one phase later.  T2 swizzle via pre-swizzled global source
// (scol ^= srow&7) + matching XOR on ds_read col-block.
// MODE 0: QKV epilogue (Q scaled / K packed short4v, V -> V^T scatter).
//         grid 768 = 3.0 rounds.
// MODE 1: Wo epilogue, fp32 float4 (C^T: 4 consecutive out-cols on r axis).
//         grid 256 = 1.0 round.
template <int MODE>
__global__ __launch_bounds__(512, 2) void gemm8(
    const short* __restrict__ A, const short* __restrict__ B,
    short* __restrict__ obf, short* __restrict__ vt, float* __restrict__ of) {
  __shared__ short As[2 * 128 * 64];   // [slot][128][64]  32 KB
  __shared__ short Bs[2 * 256 * 64];   // [slot][256][64]  64 KB
  const int tid  = threadIdx.x;
  const int w    = tid >> 6, lane = tid & 63;
  const int quad = lane >> 4, l15 = lane & 15;
  const int wr   = w >> 2, wc = w & 3;          // 2 (M=128) x 4 (N=256)
  const int fx   = l15 & 7;
  const int lid  = (int)blockIdx.x;
  // xcd = lid&7 owns a 1024-token B panel (2 MB, L2-local), walks m-tiles.
  const int xcd  = lid & 7, idx = lid >> 3;
  const int m0   = (idx >> 2) * 128;
  const int n0   = (xcd * 4 + (idx & 3)) * 256;
  const int srow = tid >> 3;
  const int scol = ((tid & 7) ^ (srow & 7)) * 8;

  const short* Ag = A + (size_t)(m0 + srow) * 1024 + scol;
  const short* Bg = B + (size_t)(n0 + srow) * 1024 + scol;

  floatx4 acc[4][4] = {};
  short8 af[4][2], bf[4][2];

#define STG_A(slot, kb) do { \
    short* _lb = &As[(slot) * 8192 + tid * 8]; \
    const short* _gp = Ag + (kb); \
    gll16(_gp, _lb); \
    gll16(_gp + (size_t)(64 * 1024), _lb + 4096); \
  } while (0)
#define STG_B(slot, kb) do { \
    short* _lb = &Bs[(slot) * 16384 + tid * 8]; \
    const short* _gp = Bg + (kb); \
    gll16(_gp,                         _lb); \
    gll16(_gp + (size_t)( 64 * 1024), _lb + 4096); \
    gll16(_gp + (size_t)(128 * 1024), _lb + 8192); \
    gll16(_gp + (size_t)(192 * 1024), _lb + 12288); \
  } while (0)
#define LDA_ALL(slot) do { \
    _Pragma("unroll") for (int ii = 0; ii < 4; ++ii) \
    _Pragma("unroll") for (int s = 0; s < 2; ++s) \
      af[ii][s] = *(const short8*)&As[(slot) * 8192 + \
          (wr * 64 + ii * 16 + l15) * 64 + ((s * 4 + quad) ^ fx) * 8]; \
  } while (0)
#define LDB_ALL(slot) do { \
    _Pragma("unroll") for (int j = 0; j < 4; ++j) \
    _Pragma("unroll") for (int s = 0; s < 2; ++s) \
      bf[j][s] = *(const short8*)&Bs[(slot) * 16384 + \
          (wc * 64 + j * 16 + l15) * 64 + ((s * 4 + quad) ^ fx) * 8]; \
  } while (0)
#define MMH(ih) do { \
    __builtin_amdgcn_s_setprio(1); \
    _Pragma("unroll") for (int i2 = 0; i2 < 2; ++i2) \
    _Pragma("unroll") for (int j = 0; j < 4; ++j) \
    _Pragma("unroll") for (int s = 0; s < 2; ++s) \
      acc[(ih) * 2 + i2][j] = __builtin_amdgcn_mfma_f32_16x16x32_bf16( \
          af[(ih) * 2 + i2][s], bf[j][s], acc[(ih) * 2 + i2][j], 0, 0, 0); \
    __builtin_amdgcn_s_setprio(0); \
  } while (0)

  // prologue: kt0 -> slot0, kt1 -> slot1 (12 loads); WV6 -> kt0's 6 landed.
  STG_B(0, 0);  STG_A(0, 0);
  STG_B(1, 64); STG_A(1, 64);
  WV6(); SBAR();

  for (int t = 0; t < 8; ++t) {
    const int kn2 = (2 * t + 2) * 64;          // -> slot0
    const int kn3 = (2 * t + 3) * 64;          // -> slot1
    const bool mre = (t < 7);
    // ---- p1: read all slot0 frags, compute M-half 0
    LDA_ALL(0); LDB_ALL(0);
    SBAR(); WLG();
    MMH(0);
    SBAR();
    // ---- p2: stage slot0 <- kt+2 (slot0 fully read in p1), compute M-half 1
    if (mre) STG_B(0, kn2);
    if (mre) STG_A(0, kn2);
    MMH(1);
    if (mre) WV6(); else WV0();                // slot1 (older 6) landed
    SBAR();
    // ---- p3: read all slot1 frags, compute M-half 0
    LDA_ALL(1); LDB_ALL(1);
    SBAR(); WLG();
    MMH(0);
    SBAR();
    // ---- p4: stage slot1 <- kt+3, compute M-half 1
    if (mre) STG_B(1, kn3);
    if (mre) STG_A(1, kn3);
    MMH(1);
    if (mre) WV6();                            // slot0 (kt+2) landed
    SBAR();
  }

  // ---- epilogue: C^T[m = out col][n = token]
  if constexpr (MODE == 0) {
    const int wsel = m0 >> 10;                  // 0=Q 1=K 2=V, uniform/block
    const int nn0  = (m0 & 1023) + wr * 64;
    if (wsel < 2) {
      const float scale = (wsel == 0) ? QSCALE : 1.0f;
      short* outw = obf + (size_t)wsel * (64u * 2048u * 64u);
#pragma unroll
      for (int i = 0; i < 4; ++i) {
        const int nn = nn0 + i * 16 + quad * 4;  // qkv col, mult of 4
        const int h = nn >> 6, d = nn & 63;
#pragma unroll
        for (int j = 0; j < 4; ++j) {
          const int tg = n0 + wc * 64 + j * 16 + l15;
          const int b = tg >> 11, tt = tg & 2047;
          short4v o4;
#pragma unroll
          for (int r = 0; r < 4; ++r) o4[r] = f2bf(acc[i][j][r] * scale);
          *(short4v*)(outw + (((size_t)(b * 16 + h) * 2048 + tt) << 6) + d) = o4;
        }
      }
    } else {
#pragma unroll
      for (int i = 0; i < 4; ++i) {
        const int nn = nn0 + i * 16 + quad * 4;  // v col in [0,1024)
        const int h = nn >> 6, d = nn & 63;
#pragma unroll
        for (int j = 0; j < 4; ++j) {
          const int tg = n0 + wc * 64 + j * 16 + l15;
          const int b = tg >> 11, tt = tg & 2047;
#pragma unroll
          for (int r = 0; r < 4; ++r)
            vt[(((size_t)(b * 16 + h) * 64 + d + r) << 11) + tt] = f2bf(acc[i][j][r]);
        }
      }
    }
  } else {
    const int nn0 = m0 + wr * 64;
#pragma unroll
    for (int i = 0; i < 4; ++i) {
      const int nn = nn0 + i * 16 + quad * 4;    // out col, 16B aligned
#pragma unroll
      for (int j = 0; j < 4; ++j) {
        const int tg = n0 + wc * 64 + j * 16 + l15;
        float4 o4;
        o4.x = acc[i][j][0]; o4.y = acc[i][j][1];
        o4.z = acc[i][j][2]; o4.w = acc[i][j][3];
        *(float4*)(of + (size_t)tg * 1024 + nn) = o4;
      }
    }
  }
#undef STG_A
#undef STG_B
#undef LDA_ALL
#undef LDB_ALL
#undef MMH
}

// -------------------------------------------------- flash attention (causal, transposed)
// grid (8, 64), block 512 (8 waves).  bh = bx + 8*(by&7) -> one XCD per bh
// group (K/V L2-local).  Block = one 256-row q-band (qb), waves 0..7 own
// 32 q rows each (strips A/B of 16; kf/vf frag reads feed both strips).
// All 8 waves share one staged K/V tile.  P chunk-interleaved (QK^T+PV per
// 32-col chunk), Ps = 2.5 KB/wave.  59.25 KB LDS -> 2 blocks/CU = 16
// waves/CU.  CU-pair balance: co-resident blocks get qb and 7-qb.
__global__ __launch_bounds__(512, 4) void attn_kernel(
    const short* __restrict__ Qg, const short* __restrict__ Kg,
    const short* __restrict__ Vt, short* __restrict__ ctx) {
  __shared__ short Ks[128 * 72];       // [t_k][d]                    18.00 KB
  __shared__ short Vs[80 * 136];       // [d][t_k], row 64 = ones     21.25 KB
  __shared__ short Ps[8 * 32 * 40];    // per-wave [q(32)][k(32)+pad] 20.00 KB

  const int tid  = threadIdx.x;
  const int w    = tid >> 6, lane = tid & 63;
  const int quad = lane >> 4, l15 = lane & 15;
  const int bh = (int)blockIdx.x + 8 * ((int)blockIdx.y & 7);
  const int g  = (int)blockIdx.y >> 3;
  const int qb = (g < 4) ? (7 - g) : (g - 4);   // CU pairs get qb + (7-qb)
  const int b  = bh >> 4, h = bh & 15;

  const size_t base = (size_t)bh * (T_SZ * 64);
  const short* Qb  = Qg + base;
  const short* Kb  = Kg + base;
  const short* Vtb = Vt + base;
  short* Pw = &Ps[w * 1280];

  // staging (512 thr): K row skr, 32B at col skp; V row svr, 32B at col svp
  const int skr = tid >> 2, skp = (tid & 3) * 16;
  const int svr = tid >> 3, svp = (tid & 7) * 16;

  // init Vs rows 64..79: row 64 = 1.0 (l-reduction), 65..79 = 0
  if (tid < 256) {
    const int rr = 64 + (tid >> 4), cb = (tid & 15) * 8;
    const short vv = (tid < 16) ? (short)0x3F80 : (short)0;
    short8 fill;
#pragma unroll
    for (int j = 0; j < 8; ++j) fill[j] = vv;
    *(short8*)&Vs[rr * 136 + cb] = fill;
  }

  const int rowA = qb * 256 + w * 32;          // strip A (16 q), strip B = +16
  const int rowB = rowA + 16;
  const int ktmax = 2 * qb + 2;

  const short8 qA0 = *(const short8*)(Qb + (size_t)(rowA + l15) * 64 + quad * 8);
  const short8 qA1 = *(const short8*)(Qb + (size_t)(rowA + l15) * 64 + 32 + quad * 8);
  const short8 qB0 = *(const short8*)(Qb + (size_t)(rowB + l15) * 64 + quad * 8);
  const short8 qB1 = *(const short8*)(Qb + (size_t)(rowB + l15) * 64 + 32 + quad * 8);

  floatx4 OA[4] = {}, OB[4] = {};
  floatx4 O5A = {}, O5B = {};                  // row: l in quad0/reg0

  // preload tile 0 into registers
  short8 kR[2], vR[2];
  kR[0] = *(const short8*)(Kb + (size_t)skr * 64 + skp);
  kR[1] = *(const short8*)(Kb + (size_t)skr * 64 + skp + 8);
  vR[0] = *(const short8*)(Vtb + (size_t)svr * 2048 + svp);
  vR[1] = *(const short8*)(Vtb + (size_t)svr * 2048 + svp + 8);

  for (int kt = 0; kt < ktmax; ++kt) {
    const int k0 = kt << 7;
    __syncthreads();                           // prior tile's LDS reads done
    *(short8*)&Ks[skr * 72 + skp]     = kR[0];
    *(short8*)&Ks[skr * 72 + skp + 8] = kR[1];
    *(short8*)&Vs[svr * 136 + svp]     = vR[0];
    *(short8*)&Vs[svr * 136 + svp + 8] = vR[1];
    if (kt + 1 < ktmax) {                      // prefetch next tile
      const int kn = (kt + 1) << 7;
      kR[0] = *(const short8*)(Kb + (size_t)(kn + skr) * 64 + skp);
      kR[1] = *(const short8*)(Kb + (size_t)(kn + skr) * 64 + skp + 8);
      vR[0] = *(const short8*)(Vtb + (size_t)svr * 2048 + kn + svp);
      vR[1] = *(const short8*)(Vtb + (size_t)svr * 2048 + kn + svp + 8);
    }
    __syncthreads();                           // staged LDS visible

    const int dkA = rowA - k0;                 // wave-uniform
    if (dkA < 0) continue;                     // tail: wave idle, barriers done
    const int dkB = dkA + 16;
    const int limA = dkA + l15, limB = limA + 16;
    const int naA = min(8, (dkA >> 4) + 1), nchA = (naA + 1) >> 1;
    const int naB = min(8, (dkB >> 4) + 1), nchB = (naB + 1) >> 1;

#pragma unroll
    for (int c = 0; c < 4; ++c) {
      if (c < nchB) {
        // ---- QK^T for the chunk's two 16-col tiles -> P LDS
#pragma unroll
        for (int mm = 0; mm < 2; ++mm) {
          const int mt = 2 * c + mm;
          const int pa = l15 * 40 + mm * 16 + quad * 4;          // strip A
          const int pb = (16 + l15) * 40 + mm * 16 + quad * 4;   // strip B
          const bool aB = (mt * 16 < dkB + 16);
          const bool aA = (mt * 16 < dkA + 16);
          if (aB) {
            const short8 kf0 = *(const short8*)&Ks[(mt * 16 + l15) * 72 + quad * 8];
            const short8 kf1 = *(const short8*)&Ks[(mt * 16 + l15) * 72 + 32 + quad * 8];
            {                                  // ---- strip B
              floatx4 s = {};
              s = __builtin_amdgcn_mfma_f32_16x16x32_bf16(kf0, qB0, s, 0, 0, 0);
              s = __builtin_amdgcn_mfma_f32_16x16x32_bf16(kf1, qB1, s, 0, 0, 0);
              if (mt * 16 + 15 > dkB) {
#pragma unroll
                for (int r = 0; r < 4; ++r)
                  if (mt * 16 + quad * 4 + r > limB) s[r] = -1e30f;
              }
              floatx4 e;
#pragma unroll
              for (int r = 0; r < 4; ++r) e[r] = fexp2(s[r]);
              uint2v pd;
              pd.x = pack_bf(e[0], e[1]);
              pd.y = pack_bf(e[2], e[3]);
              *(uint2v*)&Pw[pb] = pd;
            }
            if (c < nchA) {                    // ---- strip A (reuses kf)
              if (aA) {
                floatx4 s = {};
                s = __builtin_amdgcn_mfma_f32_16x16x32_bf16(kf0, qA0, s, 0, 0, 0);
                s = __builtin_amdgcn_mfma_f32_16x16x32_bf16(kf1, qA1, s, 0, 0, 0);
                if (mt * 16 + 15 > dkA) {
#pragma unroll
                  for (int r = 0; r < 4; ++r)
                    if (mt * 16 + quad * 4 + r > limA) s[r] = -1e30f;
                }
                floatx4 e;
#pragma unroll
                for (int r = 0; r < 4; ++r) e[r] = fexp2(s[r]);
                uint2v pd;
                pd.x = pack_bf(e[0], e[1]);
                pd.y = pack_bf(e[2], e[3]);
                *(uint2v*)&Pw[pa] = pd;
              } else {
                uint2v z; z.x = 0; z.y = 0;
                *(uint2v*)&Pw[pa] = z;
              }
            }
          } else {                             // aB false => aA false (mm==1)
            uint2v z; z.x = 0; z.y = 0;
            *(uint2v*)&Pw[pb] = z;
            if (c < nchA) *(uint2v*)&Pw[pa] = z;
          }
        }
        // ---- PV for chunk c
        const int vcol = c * 32 + quad * 8;
        const short8 vfl = *(const short8*)&Vs[(64 + l15) * 136 + vcol];
        short8 vf[4];
#pragma unroll
        for (int dt = 0; dt < 4; ++dt)
          vf[dt] = *(const short8*)&Vs[(dt * 16 + l15) * 136 + vcol];
        const short8 pfB = *(const short8*)&Pw[(16 + l15) * 40 + quad * 8];
#pragma unroll
        for (int dt = 0; dt < 4; ++dt)
          OB[dt] = __builtin_amdgcn_mfma_f32_16x16x32_bf16(vf[dt], pfB, OB[dt], 0, 0, 0);
        O5B = __builtin_amdgcn_mfma_f32_16x16x32_bf16(vfl, pfB, O5B, 0, 0, 0);
        if (c < nchA) {                        // reuses vf/vfl
          const short8 pfA = *(const short8*)&Pw[l15 * 40 + quad * 8];
#pragma unroll
          for (int dt = 0; dt < 4; ++dt)
            OA[dt] = __builtin_amdgcn_mfma_f32_16x16x32_bf16(vf[dt], pfA, OA[dt], 0, 0, 0);
          O5A = __builtin_amdgcn_mfma_f32_16x16x32_bf16(vfl, pfA, O5A, 0, 0, 0);
        }
      }
    }
  }

  // epilogue: l = O5[0] of quad0 lane l15 (C-layout row 0 = ones-row d=64)
  {
    const float lA = __shfl(O5A[0], l15);
    const float invA = 1.0f / lA;
    const int t = rowA + l15;
    short* cb = ctx + (((size_t)(b * T_SZ + t)) << 10) + h * 64 + quad * 4;
#pragma unroll
    for (int dt = 0; dt < 4; ++dt) {
      short4v o4;
#pragma unroll
      for (int r = 0; r < 4; ++r) o4[r] = f2bf(OA[dt][r] * invA);
      *(short4v*)(cb + dt * 16) = o4;
    }
  }
  {
    const float lB = __shfl(O5B[0], l15);
    const float invB = 1.0f / lB;
    const int t = rowB + l15;
    short* cb = ctx + (((size_t)(b * T_SZ + t)) << 10) + h * 64 + quad * 4;
#pragma unroll
    for (int dt = 0; dt < 4; ++dt) {
      short4v o4;
#pragma unroll
      for (int r = 0; r < 4; ++r) o4[r] = f2bf(OB[dt][r] * invB);
      *(short4v*)(cb + dt * 16) = o4;
    }
  }
}

// --------------------------------------------------
extern "C" void kernel_launch(void* const* d_in, const int* in_sizes, int n_in,
                              void* d_out, int out_size, void* d_ws, size_t ws_size,
                              hipStream_t stream) {
  const float* x  = (const float*)d_in[0];
  const float* Wq = (const float*)d_in[1];
  const float* Wk = (const float*)d_in[2];
  const float* Wv = (const float*)d_in[3];
  const float* Wo = (const float*)d_in[4];
  float* out = (float*)d_out;

  // bf16 workspace (72 MB):
  //   xb [8M]  : x bf16; dead after gemm8<0> -> reused as ctx
  //   Wt [4x1M]: transposed weights
  //   Qb,Kb [8M each] : projections [bh][t][64]
  //   Vt [8M]  : V^T [bh][64][t]  (written directly by gemm8<0> epilogue)
  short* ws  = (short*)d_ws;
  short* xb  = ws;
  short* Wt  = ws + 8388608;
  short* Qb  = Wt + 4 * 1048576;
  short* Kb  = Qb + 8388608;
  short* Vt  = Kb + 8388608;
  short* ctx = xb;

  cvt_kernel<<<dim3(32, 32, 5), dim3(32, 8), 0, stream>>>(Wq, Wk, Wv, Wo, Wt, x, xb);
  gemm8<0><<<dim3(768), 512, 0, stream>>>(Wt, xb, Qb, Vt, nullptr);
  attn_kernel<<<dim3(8, 64), 512, 0, stream>>>(Qb, Kb, Vt, ctx);
  gemm8<1><<<dim3(256), 512, 0, stream>>>(Wt + 3 * 1048576, ctx, nullptr, nullptr, out);
}